// Round 3
// baseline (1475.525 us; speedup 1.0000x reference)
//
#include <hip/hip_runtime.h>

// Problem constants (fixed by the reference file)
#define NND 50000   // nodes
#define NE  600000  // edges
#define TSEQ 50     // sequence length
#define NB  1000    // batch = NND/TSEQ

// ---------------------------------------------------------------- helpers
__device__ __forceinline__ float sigf(float x) {
    return 1.0f / (1.0f + __expf(-x));
}
__device__ __forceinline__ float tanhfast(float x) {
    x = fminf(fmaxf(x, -15.f), 15.f);
    float e = __expf(2.f * x);
    return (e - 1.f) / (e + 1.f);
}

// ---------------------------------------------------------------- degree
__global__ void k_deg(const int* __restrict__ ei, float* __restrict__ deg) {
    int e = blockIdx.x * 256 + threadIdx.x;
    if (e < NE) unsafeAtomicAdd(&deg[ei[NE + e]], 1.0f);
}

__global__ void k_dinv(float* __restrict__ deg) {
    int i = blockIdx.x * 256 + threadIdx.x;
    if (i < NND) deg[i] = 1.0f / sqrtf(deg[i] + 1.0f);
}

// ---------------------------------------------------------------- GEMM
// C[M x Nc] = A[M x 128] @ B[128 x Nc] (+bias). 64x64 tile, 256 thr, 4x4/thr.
__global__ __launch_bounds__(256) void k_gemm(
    const float* __restrict__ A, const float* __restrict__ B,
    const float* __restrict__ bias, float* __restrict__ C,
    int M, int Nc)
{
    __shared__ float As[64][65];   // [row][k], +1 pad
    __shared__ float Bs[64][64];   // [k][col]
    const int tid = threadIdx.x;
    const int tx = tid & 15, ty = tid >> 4;
    const int rowBase = blockIdx.x * 64;
    const int colBase = blockIdx.y * 64;
    float acc[4][4] = {};

    for (int kc = 0; kc < 128; kc += 64) {
        {   // stage A (coalesced float4 along k), store [row][k]
            int r  = tid >> 4;           // 0..15
            int k0 = (tid & 15) * 4;     // 0..60
            #pragma unroll
            for (int rr = 0; rr < 4; ++rr) {
                int lrow = rr * 16 + r;
                int row  = rowBase + lrow;
                float4 av = make_float4(0.f, 0.f, 0.f, 0.f);
                if (row < M) av = *(const float4*)&A[(size_t)row * 128 + kc + k0];
                As[lrow][k0 + 0] = av.x;
                As[lrow][k0 + 1] = av.y;
                As[lrow][k0 + 2] = av.z;
                As[lrow][k0 + 3] = av.w;
            }
        }
        {   // stage B
            int c0 = (tid & 15) * 4;
            #pragma unroll
            for (int it = 0; it < 4; ++it) {
                int kk = it * 16 + (tid >> 4);
                float4 bv = *(const float4*)&B[(size_t)(kc + kk) * Nc + colBase + c0];
                *(float4*)&Bs[kk][c0] = bv;
            }
        }
        __syncthreads();
        #pragma unroll
        for (int kk = 0; kk < 64; ++kk) {
            float4 bv = *(float4*)&Bs[kk][tx * 4];
            float a0 = As[ty * 4 + 0][kk];
            float a1 = As[ty * 4 + 1][kk];
            float a2 = As[ty * 4 + 2][kk];
            float a3 = As[ty * 4 + 3][kk];
            acc[0][0] += a0 * bv.x; acc[0][1] += a0 * bv.y; acc[0][2] += a0 * bv.z; acc[0][3] += a0 * bv.w;
            acc[1][0] += a1 * bv.x; acc[1][1] += a1 * bv.y; acc[1][2] += a1 * bv.z; acc[1][3] += a1 * bv.w;
            acc[2][0] += a2 * bv.x; acc[2][1] += a2 * bv.y; acc[2][2] += a2 * bv.z; acc[2][3] += a2 * bv.w;
            acc[3][0] += a3 * bv.x; acc[3][1] += a3 * bv.y; acc[3][2] += a3 * bv.z; acc[3][3] += a3 * bv.w;
        }
        __syncthreads();
    }

    int c0 = colBase + tx * 4;
    float4 bv = bias ? *(const float4*)&bias[c0] : make_float4(0.f, 0.f, 0.f, 0.f);
    #pragma unroll
    for (int i = 0; i < 4; ++i) {
        int row = rowBase + ty * 4 + i;
        if (row < M) {
            float4 o;
            o.x = acc[i][0] + bv.x;
            o.y = acc[i][1] + bv.y;
            o.z = acc[i][2] + bv.z;
            o.w = acc[i][3] + bv.w;
            *(float4*)&C[(size_t)row * Nc + c0] = o;
        }
    }
}

// ---------------------------------------------------------------- GCN pieces
__global__ void k_self(const float* __restrict__ h, const float* __restrict__ dinv,
                       float* __restrict__ agg) {
    int i = blockIdx.x * 256 + threadIdx.x;   // grid exactly NND*128
    float di = dinv[i >> 7];
    agg[i] = h[i] * di * di;
}

__global__ __launch_bounds__(256) void k_scatter(
    const int* __restrict__ ei, const float* __restrict__ h,
    const float* __restrict__ dinv, float* __restrict__ agg)
{
    int e = blockIdx.x * 2 + (threadIdx.x >> 7);
    int j = threadIdx.x & 127;
    int s = ei[e], d = ei[NE + e];
    float nm = dinv[s] * dinv[d];
    unsafeAtomicAdd(&agg[(size_t)d * 128 + j], h[(size_t)s * 128 + j] * nm);
}

__global__ void k_bias_relu(const float* __restrict__ agg, const float* __restrict__ b,
                            float* __restrict__ x) {
    int i = blockIdx.x * 256 + threadIdx.x;
    float v = agg[i] + b[i & 127];
    x[i] = v > 0.f ? v : 0.f;
}

// ---------------------------------------------------------------- LSTM prep
// Pack w (512x128 row-major, row r=g*128+j) into wp[k*512 + j*4 + g] so one
// float4 read at (k, j) yields (i,f,g,o) weights for hidden unit j.
__global__ void k_prep(const float* __restrict__ w_ih, const float* __restrict__ w_hh,
                       const float* __restrict__ b_ih, const float* __restrict__ b_hh,
                       float* __restrict__ wp_ih, float* __restrict__ wp_hh,
                       float* __restrict__ bp)
{
    int t = blockIdx.x * 256 + threadIdx.x;
    if (t < 65536) {
        int r = t >> 7, k = t & 127;
        int g = r >> 7, j = r & 127;
        wp_ih[k * 512 + (j << 2) + g] = w_ih[t];
    } else if (t < 131072) {
        int t2 = t - 65536;
        int r = t2 >> 7, k = t2 & 127;
        int g = r >> 7, j = r & 127;
        wp_hh[k * 512 + (j << 2) + g] = w_hh[t2];
    } else if (t < 131584) {
        int r = t - 131072;   // 0..511
        int g = r >> 7, j = r & 127;
        bp[(j << 2) + g] = b_ih[r] + b_hh[r];
    }
}

// ---------------------------------------------------------------- LSTM recurrence
// v3: weights FORCED into VGPRs via opaque asm (v2's loads were sunk back into
// the step loop by the compiler -> VGPR_Count was 84, re-streaming from L2).
// 512 threads/WG, 4 batch elems/WG, 250 WGs (1 WG/CU, 2 waves/SIMD).
// Phase 1: thread t owns packed gate-col t; 128 loop-invariant w_hh weights in
//   registers; h streamed from LDS via wave-uniform broadcast ds_read_b128.
// Phase 2: thread t remaps to (j=t&127, b=t>>7); c-state in a register.
__global__ __launch_bounds__(512, 2) void k_lstm(
    const float* __restrict__ G,    // (NB*TSEQ) x 512, gate-packed cols
    const float* __restrict__ wp,   // 128 x 512, gate-packed
    float* __restrict__ Hout)       // (NB*TSEQ) x 128
{
    const int t  = threadIdx.x;       // 0..511 = packed gate column
    const int j  = t & 127;           // phase-2 hidden unit
    const int b  = t >> 7;            // phase-2 batch slot
    const int b0 = blockIdx.x * 4;

    __shared__ float h_s[4][128];     // [batch][hidden]
    __shared__ float part[4][512];    // [batch][packed gate col]

    // Load the thread's weight column into registers and pin it there: the
    // empty asm is an opaque identity, so the compiler cannot rematerialize
    // these values by re-loading wp inside the step loop.
    float4 wreg[32];
    #pragma unroll
    for (int k2 = 0; k2 < 32; ++k2) {
        float4 w;
        w.x = wp[(size_t)(k2 * 4 + 0) * 512 + t];
        w.y = wp[(size_t)(k2 * 4 + 1) * 512 + t];
        w.z = wp[(size_t)(k2 * 4 + 2) * 512 + t];
        w.w = wp[(size_t)(k2 * 4 + 3) * 512 + t];
        asm volatile("" : "+v"(w.x), "+v"(w.y), "+v"(w.z), "+v"(w.w));
        wreg[k2] = w;
    }

    h_s[b][j] = 0.f;
    float c = 0.f;
    __syncthreads();

    const float* gbase = &G[(((size_t)(b0 + b)) * TSEQ) * 512 + (j << 2)];

    for (int step = 0; step < TSEQ; ++step) {
        // prefetch this thread's gate-input quad (phase-2 mapping)
        const float4 gv = *(const float4*)&gbase[(size_t)step * 512];

        // phase 1: acc[b'] = sum_k h[b'][k] * w[k][t]
        float acc0 = 0.f, acc1 = 0.f, acc2 = 0.f, acc3 = 0.f;
        #pragma unroll
        for (int k2 = 0; k2 < 32; ++k2) {
            const float4 w = wreg[k2];
            float4 hv;
            hv = *(const float4*)&h_s[0][k2 * 4];
            acc0 += hv.x * w.x + hv.y * w.y + hv.z * w.z + hv.w * w.w;
            hv = *(const float4*)&h_s[1][k2 * 4];
            acc1 += hv.x * w.x + hv.y * w.y + hv.z * w.z + hv.w * w.w;
            hv = *(const float4*)&h_s[2][k2 * 4];
            acc2 += hv.x * w.x + hv.y * w.y + hv.z * w.z + hv.w * w.w;
            hv = *(const float4*)&h_s[3][k2 * 4];
            acc3 += hv.x * w.x + hv.y * w.y + hv.z * w.z + hv.w * w.w;
        }
        part[0][t] = acc0;
        part[1][t] = acc1;
        part[2][t] = acc2;
        part[3][t] = acc3;
        __syncthreads();

        // phase 2: thread (j,b) applies the LSTM cell
        const float4 pa = *(const float4*)&part[b][j << 2];
        float xi = pa.x + gv.x;
        float xf = pa.y + gv.y;
        float xg = pa.z + gv.z;
        float xo = pa.w + gv.w;
        float ii = sigf(xi), ff = sigf(xf), gg = tanhfast(xg), oo = sigf(xo);
        float cn = ff * c + ii * gg;
        c = cn;
        float hn = oo * tanhfast(cn);
        h_s[b][j] = hn;
        Hout[(((size_t)(b0 + b)) * TSEQ + step) * 128 + j] = hn;
        __syncthreads();
    }
}

// ---------------------------------------------------------------- FC head
__global__ __launch_bounds__(256) void k_fc(
    const float* __restrict__ seq, const float* __restrict__ fcw,
    const float* __restrict__ fcb, float* __restrict__ out)
{
    int b    = blockIdx.x * 4 + (threadIdx.x >> 6);
    int lane = threadIdx.x & 63;
    const float* row = &seq[(((size_t)b) * TSEQ + (TSEQ - 1)) * 128];
    float v = row[lane] * fcw[lane] + row[lane + 64] * fcw[lane + 64];
    #pragma unroll
    for (int off = 32; off > 0; off >>= 1)
        v += __shfl_down(v, off);
    if (lane == 0) out[b] = v + fcb[0];
}

// ---------------------------------------------------------------- launch
extern "C" void kernel_launch(void* const* d_in, const int* in_sizes, int n_in,
                              void* d_out, int out_size, void* d_ws, size_t ws_size,
                              hipStream_t stream)
{
    const float* x    = (const float*)d_in[0];
    const int*   ei   = (const int*)d_in[1];
    const float* W1   = (const float*)d_in[3];
    const float* b1   = (const float*)d_in[4];
    const float* W2   = (const float*)d_in[5];
    const float* b2   = (const float*)d_in[6];
    const float* fcw  = (const float*)d_in[7];
    const float* fcb  = (const float*)d_in[8];
    const float* wih0 = (const float*)d_in[9];
    const float* whh0 = (const float*)d_in[10];
    const float* bih0 = (const float*)d_in[11];
    const float* bhh0 = (const float*)d_in[12];
    const float* wih1 = (const float*)d_in[13];
    const float* whh1 = (const float*)d_in[14];
    const float* bih1 = (const float*)d_in[15];
    const float* bhh1 = (const float*)d_in[16];
    float* out = (float*)d_out;

    char* ws = (char*)d_ws;
    float* bufH  = (float*)(ws + 0);           // 25.6 MB  (h pre-agg / seq0)
    float* bufX  = (float*)(ws + 25600000);    // 25.6 MB  (agg / X / seq1)
    float* bufG  = (float*)(ws + 51200000);    // 102.4 MB (gates)
    float* dinv  = (float*)(ws + 153600000);   // 0.2 MB   (deg -> dinv in place)
    float* wpih0 = (float*)(ws + 153800192);
    float* wphh0 = (float*)(ws + 154062336);
    float* wpih1 = (float*)(ws + 154324480);
    float* wphh1 = (float*)(ws + 154586624);
    float* bp0   = (float*)(ws + 154848768);
    float* bp1   = (float*)(ws + 154850816);

    // degree -> dinv
    hipMemsetAsync(dinv, 0, NND * sizeof(float), stream);
    k_deg<<<(NE + 255) / 256, 256, 0, stream>>>(ei, dinv);
    k_dinv<<<(NND + 255) / 256, 256, 0, stream>>>(dinv);

    // pack LSTM weights
    k_prep<<<514, 256, 0, stream>>>(wih0, whh0, bih0, bhh0, wpih0, wphh0, bp0);
    k_prep<<<514, 256, 0, stream>>>(wih1, whh1, bih1, bhh1, wpih1, wphh1, bp1);

    dim3 gH((NND + 63) / 64, 2);   // 128-col GEMMs
    dim3 gG((NND + 63) / 64, 8);   // 512-col GEMMs

    // GCN layer 1
    k_gemm<<<gH, 256, 0, stream>>>(x, W1, nullptr, bufH, NND, 128);
    k_self<<<NND * 128 / 256, 256, 0, stream>>>(bufH, dinv, bufX);
    k_scatter<<<NE / 2, 256, 0, stream>>>(ei, bufH, dinv, bufX);
    k_bias_relu<<<NND * 128 / 256, 256, 0, stream>>>(bufX, b1, bufX);

    // GCN layer 2
    k_gemm<<<gH, 256, 0, stream>>>(bufX, W2, nullptr, bufH, NND, 128);
    k_self<<<NND * 128 / 256, 256, 0, stream>>>(bufH, dinv, bufX);
    k_scatter<<<NE / 2, 256, 0, stream>>>(ei, bufH, dinv, bufX);
    k_bias_relu<<<NND * 128 / 256, 256, 0, stream>>>(bufX, b2, bufX);

    // LSTM layer 0: gates for all timesteps, then recurrence (seq out -> bufH)
    k_gemm<<<gG, 256, 0, stream>>>(bufX, wpih0, bp0, bufG, NND, 512);
    k_lstm<<<NB / 4, 512, 0, stream>>>(bufG, wphh0, bufH);

    // LSTM layer 1 (seq out -> bufX)
    k_gemm<<<gG, 256, 0, stream>>>(bufH, wpih1, bp1, bufG, NND, 512);
    k_lstm<<<NB / 4, 512, 0, stream>>>(bufG, wphh1, bufX);

    // FC head
    k_fc<<<NB / 4, 256, 0, stream>>>(bufX, fcw, fcb, out);
}

// Round 4
// 1421.805 us; speedup vs baseline: 1.0378x; 1.0378x over previous
//
#include <hip/hip_runtime.h>

// Problem constants (fixed by the reference file)
#define NND 50000   // nodes
#define NE  600000  // edges
#define TSEQ 50     // sequence length
#define NB  1000    // batch = NND/TSEQ

typedef __attribute__((ext_vector_type(4))) float f32x4;
typedef __attribute__((ext_vector_type(8))) short s16x8;

// ---------------------------------------------------------------- helpers
__device__ __forceinline__ float sigf(float x) {
    return 1.0f / (1.0f + __expf(-x));
}
__device__ __forceinline__ float tanhfast(float x) {
    x = fminf(fmaxf(x, -15.f), 15.f);
    float e = __expf(2.f * x);
    return (e - 1.f) / (e + 1.f);
}
// bf16 bit helpers (round-to-nearest-even)
__device__ __forceinline__ unsigned short f2bf(float f) {
    unsigned int u = __float_as_uint(f);
    u = u + 0x7FFFu + ((u >> 16) & 1u);
    return (unsigned short)(u >> 16);
}
__device__ __forceinline__ float bf2f(unsigned short h) {
    return __uint_as_float(((unsigned int)h) << 16);
}

// ---------------------------------------------------------------- degree
__global__ void k_deg(const int* __restrict__ ei, float* __restrict__ deg) {
    int e = blockIdx.x * 256 + threadIdx.x;
    if (e < NE) unsafeAtomicAdd(&deg[ei[NE + e]], 1.0f);
}

__global__ void k_dinv(float* __restrict__ deg) {
    int i = blockIdx.x * 256 + threadIdx.x;
    if (i < NND) deg[i] = 1.0f / sqrtf(deg[i] + 1.0f);
}

// ---------------------------------------------------------------- cvt fp32 -> split bf16
__global__ void k_cvt(const float* __restrict__ in, unsigned short* __restrict__ hi,
                      unsigned short* __restrict__ lo, int n4) {
    int i = blockIdx.x * 256 + threadIdx.x;
    if (i >= n4) return;
    float4 v = ((const float4*)in)[i];
    ushort4 h, l;
    h.x = f2bf(v.x); l.x = f2bf(v.x - bf2f(h.x));
    h.y = f2bf(v.y); l.y = f2bf(v.y - bf2f(h.y));
    h.z = f2bf(v.z); l.z = f2bf(v.z - bf2f(h.z));
    h.w = f2bf(v.w); l.w = f2bf(v.w - bf2f(h.w));
    ((ushort4*)hi)[i] = h;
    ((ushort4*)lo)[i] = l;
}

// ---------------------------------------------------------------- MFMA GEMM
// C[M x Nc] = A[M x 128] @ B[128 x Nc] + bias, split-bf16 (3 MFMAs / tile).
// A given as hi/lo bf16 [M][128]; B given TRANSPOSED n-major hi/lo [Nc][128].
// 256 thr, tile 128x64, 4 waves: wave = (mw = w&1 -> 64 rows, nw = w>>1 -> 32 cols).
__global__ __launch_bounds__(256) void k_gemm_mfma(
    const unsigned short* __restrict__ Ahi, const unsigned short* __restrict__ Alo,
    const unsigned short* __restrict__ Bhi, const unsigned short* __restrict__ Blo,
    const float* __restrict__ bias, float* __restrict__ C,
    int M, int Nc)
{
    __shared__ unsigned short As_hi[128][72];
    __shared__ unsigned short As_lo[128][72];
    __shared__ unsigned short Bs_hi[64][72];
    __shared__ unsigned short Bs_lo[64][72];

    const int tid  = threadIdx.x;
    const int lane = tid & 63, wave = tid >> 6;
    const int mw = wave & 1, nw = wave >> 1;
    const int l15 = lane & 15, quad = lane >> 4;
    const int rowBase = blockIdx.x * 128;
    const int colBase = blockIdx.y * 64;

    f32x4 acc[4][2] = {};

    for (int kc = 0; kc < 128; kc += 64) {
        // stage A (128 rows x 64 k) and B (64 n-rows x 64 k), 16B copies
        int lr = tid >> 3;            // 0..31
        int ko = (tid & 7) * 8;       // 0..56
        #pragma unroll
        for (int i = 0; i < 4; ++i) {
            int row = lr + i * 32;
            int g = rowBase + row;
            uint4 vh = make_uint4(0, 0, 0, 0), vl = make_uint4(0, 0, 0, 0);
            if (g < M) {
                vh = *(const uint4*)&Ahi[(size_t)g * 128 + kc + ko];
                vl = *(const uint4*)&Alo[(size_t)g * 128 + kc + ko];
            }
            *(uint4*)&As_hi[row][ko] = vh;
            *(uint4*)&As_lo[row][ko] = vl;
        }
        #pragma unroll
        for (int i = 0; i < 2; ++i) {
            int row = lr + i * 32;        // n within tile (Nc is a multiple of 64)
            int g = colBase + row;
            uint4 vh = *(const uint4*)&Bhi[(size_t)g * 128 + kc + ko];
            uint4 vl = *(const uint4*)&Blo[(size_t)g * 128 + kc + ko];
            *(uint4*)&Bs_hi[row][ko] = vh;
            *(uint4*)&Bs_lo[row][ko] = vl;
        }
        __syncthreads();

        #pragma unroll
        for (int kq = 0; kq < 2; ++kq) {
            int kof = kq * 32 + quad * 8;
            s16x8 ah[4], al[4], bh[2], bl[2];
            #pragma unroll
            for (int ms = 0; ms < 4; ++ms) {
                int r = mw * 64 + ms * 16 + l15;
                ah[ms] = *(const s16x8*)&As_hi[r][kof];
                al[ms] = *(const s16x8*)&As_lo[r][kof];
            }
            #pragma unroll
            for (int ns = 0; ns < 2; ++ns) {
                int r = nw * 32 + ns * 16 + l15;
                bh[ns] = *(const s16x8*)&Bs_hi[r][kof];
                bl[ns] = *(const s16x8*)&Bs_lo[r][kof];
            }
            #pragma unroll
            for (int ms = 0; ms < 4; ++ms)
                #pragma unroll
                for (int ns = 0; ns < 2; ++ns)
                    acc[ms][ns] = __builtin_amdgcn_mfma_f32_16x16x32_bf16(ah[ms], bh[ns], acc[ms][ns], 0, 0, 0);
            #pragma unroll
            for (int ms = 0; ms < 4; ++ms)
                #pragma unroll
                for (int ns = 0; ns < 2; ++ns)
                    acc[ms][ns] = __builtin_amdgcn_mfma_f32_16x16x32_bf16(al[ms], bh[ns], acc[ms][ns], 0, 0, 0);
            #pragma unroll
            for (int ms = 0; ms < 4; ++ms)
                #pragma unroll
                for (int ns = 0; ns < 2; ++ns)
                    acc[ms][ns] = __builtin_amdgcn_mfma_f32_16x16x32_bf16(ah[ms], bl[ns], acc[ms][ns], 0, 0, 0);
        }
        __syncthreads();
    }

    // epilogue: C/D layout col=lane&15, row=quad*4+reg
    #pragma unroll
    for (int ns = 0; ns < 2; ++ns) {
        int col = colBase + nw * 32 + ns * 16 + l15;
        float bv = bias ? bias[col] : 0.f;
        #pragma unroll
        for (int ms = 0; ms < 4; ++ms) {
            int row0 = rowBase + mw * 64 + ms * 16 + quad * 4;
            #pragma unroll
            for (int r = 0; r < 4; ++r) {
                int row = row0 + r;
                if (row < M) C[(size_t)row * Nc + col] = acc[ms][ns][r] + bv;
            }
        }
    }
}

// ---------------------------------------------------------------- GCN pieces
__global__ void k_self(const float* __restrict__ h, const float* __restrict__ dinv,
                       float* __restrict__ agg) {
    int i = blockIdx.x * 256 + threadIdx.x;   // grid exactly NND*128
    float di = dinv[i >> 7];
    agg[i] = h[i] * di * di;
}

__global__ __launch_bounds__(256) void k_scatter(
    const int* __restrict__ ei, const float* __restrict__ h,
    const float* __restrict__ dinv, float* __restrict__ agg)
{
    int e = blockIdx.x * 2 + (threadIdx.x >> 7);
    int j = threadIdx.x & 127;
    int s = ei[e], d = ei[NE + e];
    float nm = dinv[s] * dinv[d];
    unsafeAtomicAdd(&agg[(size_t)d * 128 + j], h[(size_t)s * 128 + j] * nm);
}

// bias + relu + split-bf16 conversion (output feeds the next MFMA GEMM)
__global__ void k_bias_relu_cvt(const float* __restrict__ agg, const float* __restrict__ b,
                                unsigned short* __restrict__ hi, unsigned short* __restrict__ lo) {
    int i = blockIdx.x * 256 + threadIdx.x;   // grid NND*128/4
    float4 v = ((const float4*)agg)[i];
    float4 bb = *(const float4*)&b[(i * 4) & 127];
    v.x = fmaxf(v.x + bb.x, 0.f);
    v.y = fmaxf(v.y + bb.y, 0.f);
    v.z = fmaxf(v.z + bb.z, 0.f);
    v.w = fmaxf(v.w + bb.w, 0.f);
    ushort4 h, l;
    h.x = f2bf(v.x); l.x = f2bf(v.x - bf2f(h.x));
    h.y = f2bf(v.y); l.y = f2bf(v.y - bf2f(h.y));
    h.z = f2bf(v.z); l.z = f2bf(v.z - bf2f(h.z));
    h.w = f2bf(v.w); l.w = f2bf(v.w - bf2f(h.w));
    ((ushort4*)hi)[i] = h;
    ((ushort4*)lo)[i] = l;
}

// ---------------------------------------------------------------- prep kernels
// GCN weight W [128(k)][128(n)] fp32 -> transposed n-major split-bf16 [n][k]
__global__ void k_prep_gcnw(const float* __restrict__ W,
                            unsigned short* __restrict__ hi, unsigned short* __restrict__ lo) {
    int t = blockIdx.x * 256 + threadIdx.x;
    if (t >= 16384) return;
    int k = t >> 7, n = t & 127;
    float v = W[t];
    unsigned short h = f2bf(v);
    hi[n * 128 + k] = h;
    lo[n * 128 + k] = f2bf(v - bf2f(h));
}

// LSTM prep: w_ih [512(r=g*128+j)][128(k)] -> packed-transposed split-bf16
// wpT[p=j*4+g][k]; w_hh -> fp32 packed [k][512] (for the recurrence kernel);
// bias -> bp[p] = b_ih + b_hh.
__global__ void k_prep_lstm(const float* __restrict__ w_ih, const float* __restrict__ w_hh,
                            const float* __restrict__ b_ih, const float* __restrict__ b_hh,
                            unsigned short* __restrict__ wpT_hi, unsigned short* __restrict__ wpT_lo,
                            float* __restrict__ wp_hh, float* __restrict__ bp)
{
    int t = blockIdx.x * 256 + threadIdx.x;
    if (t < 65536) {
        int r = t >> 7, k = t & 127;
        int g = r >> 7, j = r & 127;
        int p = (j << 2) + g;
        float v = w_ih[t];
        unsigned short h = f2bf(v);
        wpT_hi[p * 128 + k] = h;
        wpT_lo[p * 128 + k] = f2bf(v - bf2f(h));
    } else if (t < 131072) {
        int t2 = t - 65536;
        int r = t2 >> 7, k = t2 & 127;
        int g = r >> 7, j = r & 127;
        wp_hh[k * 512 + (j << 2) + g] = w_hh[t2];
    } else if (t < 131584) {
        int r = t - 131072;   // 0..511
        int g = r >> 7, j = r & 127;
        bp[(j << 2) + g] = b_ih[r] + b_hh[r];
    }
}

// ---------------------------------------------------------------- LSTM recurrence
// (v2 structure; LDS-pipe bound ~280us — redesign is a future round)
__global__ __launch_bounds__(512, 2) void k_lstm(
    const float* __restrict__ G,    // (NB*TSEQ) x 512, gate-packed cols
    const float* __restrict__ wp,   // 128 x 512, gate-packed
    float* __restrict__ Hout)       // (NB*TSEQ) x 128
{
    const int t  = threadIdx.x;       // 0..511 = packed gate column
    const int j  = t & 127;           // phase-2 hidden unit
    const int b  = t >> 7;            // phase-2 batch slot
    const int b0 = blockIdx.x * 4;

    __shared__ float h_s[4][128];     // [batch][hidden]
    __shared__ float part[4][512];    // [batch][packed gate col]

    float4 wreg[32];
    #pragma unroll
    for (int k2 = 0; k2 < 32; ++k2) {
        float4 w;
        w.x = wp[(size_t)(k2 * 4 + 0) * 512 + t];
        w.y = wp[(size_t)(k2 * 4 + 1) * 512 + t];
        w.z = wp[(size_t)(k2 * 4 + 2) * 512 + t];
        w.w = wp[(size_t)(k2 * 4 + 3) * 512 + t];
        wreg[k2] = w;
    }

    h_s[b][j] = 0.f;
    float c = 0.f;
    __syncthreads();

    const float* gbase = &G[(((size_t)(b0 + b)) * TSEQ) * 512 + (j << 2)];

    for (int step = 0; step < TSEQ; ++step) {
        const float4 gv = *(const float4*)&gbase[(size_t)step * 512];

        float acc0 = 0.f, acc1 = 0.f, acc2 = 0.f, acc3 = 0.f;
        #pragma unroll
        for (int k2 = 0; k2 < 32; ++k2) {
            const float4 w = wreg[k2];
            float4 hv;
            hv = *(const float4*)&h_s[0][k2 * 4];
            acc0 += hv.x * w.x + hv.y * w.y + hv.z * w.z + hv.w * w.w;
            hv = *(const float4*)&h_s[1][k2 * 4];
            acc1 += hv.x * w.x + hv.y * w.y + hv.z * w.z + hv.w * w.w;
            hv = *(const float4*)&h_s[2][k2 * 4];
            acc2 += hv.x * w.x + hv.y * w.y + hv.z * w.z + hv.w * w.w;
            hv = *(const float4*)&h_s[3][k2 * 4];
            acc3 += hv.x * w.x + hv.y * w.y + hv.z * w.z + hv.w * w.w;
        }
        part[0][t] = acc0;
        part[1][t] = acc1;
        part[2][t] = acc2;
        part[3][t] = acc3;
        __syncthreads();

        const float4 pa = *(const float4*)&part[b][j << 2];
        float xi = pa.x + gv.x;
        float xf = pa.y + gv.y;
        float xg = pa.z + gv.z;
        float xo = pa.w + gv.w;
        float ii = sigf(xi), ff = sigf(xf), gg = tanhfast(xg), oo = sigf(xo);
        float cn = ff * c + ii * gg;
        c = cn;
        float hn = oo * tanhfast(cn);
        h_s[b][j] = hn;
        Hout[(((size_t)(b0 + b)) * TSEQ + step) * 128 + j] = hn;
        __syncthreads();
    }
}

// ---------------------------------------------------------------- FC head
__global__ __launch_bounds__(256) void k_fc(
    const float* __restrict__ seq, const float* __restrict__ fcw,
    const float* __restrict__ fcb, float* __restrict__ out)
{
    int b    = blockIdx.x * 4 + (threadIdx.x >> 6);
    int lane = threadIdx.x & 63;
    const float* row = &seq[(((size_t)b) * TSEQ + (TSEQ - 1)) * 128];
    float v = row[lane] * fcw[lane] + row[lane + 64] * fcw[lane + 64];
    #pragma unroll
    for (int off = 32; off > 0; off >>= 1)
        v += __shfl_down(v, off);
    if (lane == 0) out[b] = v + fcb[0];
}

// ---------------------------------------------------------------- launch
extern "C" void kernel_launch(void* const* d_in, const int* in_sizes, int n_in,
                              void* d_out, int out_size, void* d_ws, size_t ws_size,
                              hipStream_t stream)
{
    const float* x    = (const float*)d_in[0];
    const int*   ei   = (const int*)d_in[1];
    const float* W1   = (const float*)d_in[3];
    const float* b1   = (const float*)d_in[4];
    const float* W2   = (const float*)d_in[5];
    const float* b2   = (const float*)d_in[6];
    const float* fcw  = (const float*)d_in[7];
    const float* fcb  = (const float*)d_in[8];
    const float* wih0 = (const float*)d_in[9];
    const float* whh0 = (const float*)d_in[10];
    const float* bih0 = (const float*)d_in[11];
    const float* bhh0 = (const float*)d_in[12];
    const float* wih1 = (const float*)d_in[13];
    const float* whh1 = (const float*)d_in[14];
    const float* bih1 = (const float*)d_in[15];
    const float* bhh1 = (const float*)d_in[16];
    float* out = (float*)d_out;

    char* ws = (char*)d_ws;
    float* bufH = (float*)(ws + 0);           // 25.6 MB fp32 (h pre-agg; later S-hi/lo home)
    float* bufX = (float*)(ws + 25600000);    // 25.6 MB fp32 (agg / seq)
    float* bufG = (float*)(ws + 51200000);    // 102.4 MB fp32 (gates; early: A-hi/lo home)

    // split-bf16 A operands (12.8 MB each). Early phase: in bufG region.
    unsigned short* xhi = (unsigned short*)(ws + 51200000);
    unsigned short* xlo = (unsigned short*)(ws + 64000000);
    // gate-GEMM A operands live in bufH region (bufH free by then)
    unsigned short* shi = (unsigned short*)(ws + 0);
    unsigned short* slo = (unsigned short*)(ws + 12800000);

    float* dinv  = (float*)(ws + 153600000);
    float* wphh0 = (float*)(ws + 153800192);
    float* wphh1 = (float*)(ws + 154062336);
    float* bp0   = (float*)(ws + 154324480);
    float* bp1   = (float*)(ws + 154326528);
    unsigned short* w1t_hi   = (unsigned short*)(ws + 154328576);
    unsigned short* w1t_lo   = (unsigned short*)(ws + 154361344);
    unsigned short* w2t_hi   = (unsigned short*)(ws + 154394112);
    unsigned short* w2t_lo   = (unsigned short*)(ws + 154426880);
    unsigned short* wpih0_hi = (unsigned short*)(ws + 154459648);
    unsigned short* wpih0_lo = (unsigned short*)(ws + 154590720);
    unsigned short* wpih1_hi = (unsigned short*)(ws + 154721792);
    unsigned short* wpih1_lo = (unsigned short*)(ws + 154852864);

    // degree -> dinv
    hipMemsetAsync(dinv, 0, NND * sizeof(float), stream);
    k_deg<<<(NE + 255) / 256, 256, 0, stream>>>(ei, dinv);
    k_dinv<<<(NND + 255) / 256, 256, 0, stream>>>(dinv);

    // weight prep
    k_prep_gcnw<<<64, 256, 0, stream>>>(W1, w1t_hi, w1t_lo);
    k_prep_gcnw<<<64, 256, 0, stream>>>(W2, w2t_hi, w2t_lo);
    k_prep_lstm<<<514, 256, 0, stream>>>(wih0, whh0, bih0, bhh0, wpih0_hi, wpih0_lo, wphh0, bp0);
    k_prep_lstm<<<514, 256, 0, stream>>>(wih1, whh1, bih1, bhh1, wpih1_hi, wpih1_lo, wphh1, bp1);

    dim3 gH(391, 2);   // 128-col GEMMs (ceil(50000/128)=391)
    dim3 gG(391, 8);   // 512-col GEMMs

    // GCN layer 1
    k_cvt<<<6250, 256, 0, stream>>>(x, xhi, xlo, NND * 128 / 4);
    k_gemm_mfma<<<gH, 256, 0, stream>>>(xhi, xlo, w1t_hi, w1t_lo, nullptr, bufH, NND, 128);
    k_self<<<NND * 128 / 256, 256, 0, stream>>>(bufH, dinv, bufX);
    k_scatter<<<NE / 2, 256, 0, stream>>>(ei, bufH, dinv, bufX);
    k_bias_relu_cvt<<<NND * 128 / 1024, 256, 0, stream>>>(bufX, b1, xhi, xlo);

    // GCN layer 2
    k_gemm_mfma<<<gH, 256, 0, stream>>>(xhi, xlo, w2t_hi, w2t_lo, nullptr, bufH, NND, 128);
    k_self<<<NND * 128 / 256, 256, 0, stream>>>(bufH, dinv, bufX);
    k_scatter<<<NE / 2, 256, 0, stream>>>(ei, bufH, dinv, bufX);
    // relu output -> bufH region (h2 dead after scatter); feeds gate GEMM 0
    k_bias_relu_cvt<<<NND * 128 / 1024, 256, 0, stream>>>(bufX, b2, shi, slo);

    // LSTM layer 0: gate GEMM (bf16 MFMA) + recurrence
    k_gemm_mfma<<<gG, 256, 0, stream>>>(shi, slo, wpih0_hi, wpih0_lo, bp0, bufG, NND, 512);
    k_lstm<<<NB / 4, 512, 0, stream>>>(bufG, wphh0, bufX);     // seq0 -> bufX

    // LSTM layer 1
    k_cvt<<<6250, 256, 0, stream>>>(bufX, shi, slo, NND * 128 / 4);
    k_gemm_mfma<<<gG, 256, 0, stream>>>(shi, slo, wpih1_hi, wpih1_lo, bp1, bufG, NND, 512);
    k_lstm<<<NB / 4, 512, 0, stream>>>(bufG, wphh1, bufX);     // seq1 -> bufX (seq0 dead)

    // FC head
    k_fc<<<NB / 4, 256, 0, stream>>>(bufX, fcw, fcb, out);
}

// Round 6
// 1172.178 us; speedup vs baseline: 1.2588x; 1.2130x over previous
//
#include <hip/hip_runtime.h>

// Problem constants (fixed by the reference file)
#define NND 50000   // nodes
#define NE  600000  // edges
#define TSEQ 50     // sequence length
#define NB  1000    // batch = NND/TSEQ
#define SB  16      // sequences per LSTM workgroup
#define AHS 136     // LDS h-row stride in shorts (128 + 8 pad, 16B-aligned)

typedef __attribute__((ext_vector_type(4))) float f32x4;
typedef __attribute__((ext_vector_type(8))) short s16x8;

// ---------------------------------------------------------------- helpers
__device__ __forceinline__ float sigf(float x) {
    return 1.0f / (1.0f + __expf(-x));
}
__device__ __forceinline__ float tanhfast(float x) {
    x = fminf(fmaxf(x, -15.f), 15.f);
    float e = __expf(2.f * x);
    return (e - 1.f) / (e + 1.f);
}
// bf16 bit helpers (round-to-nearest-even)
__device__ __forceinline__ unsigned short f2bf(float f) {
    unsigned int u = __float_as_uint(f);
    u = u + 0x7FFFu + ((u >> 16) & 1u);
    return (unsigned short)(u >> 16);
}
__device__ __forceinline__ float bf2f(unsigned short h) {
    return __uint_as_float(((unsigned int)h) << 16);
}

// ---------------------------------------------------------------- degree
__global__ void k_deg(const int* __restrict__ ei, float* __restrict__ deg) {
    int e = blockIdx.x * 256 + threadIdx.x;
    if (e < NE) unsafeAtomicAdd(&deg[ei[NE + e]], 1.0f);
}

__global__ void k_dinv(float* __restrict__ deg) {
    int i = blockIdx.x * 256 + threadIdx.x;
    if (i < NND) deg[i] = 1.0f / sqrtf(deg[i] + 1.0f);
}

// ---------------------------------------------------------------- cvt fp32 -> split bf16
__global__ void k_cvt(const float* __restrict__ in, unsigned short* __restrict__ hi,
                      unsigned short* __restrict__ lo, int n4) {
    int i = blockIdx.x * 256 + threadIdx.x;
    if (i >= n4) return;
    float4 v = ((const float4*)in)[i];
    ushort4 h, l;
    h.x = f2bf(v.x); l.x = f2bf(v.x - bf2f(h.x));
    h.y = f2bf(v.y); l.y = f2bf(v.y - bf2f(h.y));
    h.z = f2bf(v.z); l.z = f2bf(v.z - bf2f(h.z));
    h.w = f2bf(v.w); l.w = f2bf(v.w - bf2f(h.w));
    ((ushort4*)hi)[i] = h;
    ((ushort4*)lo)[i] = l;
}

// ---------------------------------------------------------------- MFMA GEMM
// C[M x Nc] = A[M x 128] @ B[128 x Nc] + bias, split-bf16 (3 MFMAs / tile).
// A given as hi/lo bf16 [M][128]; B given TRANSPOSED n-major hi/lo [Nc][128].
// 256 thr, tile 128x64, 4 waves: wave = (mw = w&1 -> 64 rows, nw = w>>1 -> 32 cols).
__global__ __launch_bounds__(256) void k_gemm_mfma(
    const unsigned short* __restrict__ Ahi, const unsigned short* __restrict__ Alo,
    const unsigned short* __restrict__ Bhi, const unsigned short* __restrict__ Blo,
    const float* __restrict__ bias, float* __restrict__ C,
    int M, int Nc)
{
    __shared__ unsigned short As_hi[128][72];
    __shared__ unsigned short As_lo[128][72];
    __shared__ unsigned short Bs_hi[64][72];
    __shared__ unsigned short Bs_lo[64][72];

    const int tid  = threadIdx.x;
    const int lane = tid & 63, wave = tid >> 6;
    const int mw = wave & 1, nw = wave >> 1;
    const int l15 = lane & 15, quad = lane >> 4;
    const int rowBase = blockIdx.x * 128;
    const int colBase = blockIdx.y * 64;

    f32x4 acc[4][2] = {};

    for (int kc = 0; kc < 128; kc += 64) {
        // stage A (128 rows x 64 k) and B (64 n-rows x 64 k), 16B copies
        int lr = tid >> 3;            // 0..31
        int ko = (tid & 7) * 8;       // 0..56
        #pragma unroll
        for (int i = 0; i < 4; ++i) {
            int row = lr + i * 32;
            int g = rowBase + row;
            uint4 vh = make_uint4(0, 0, 0, 0), vl = make_uint4(0, 0, 0, 0);
            if (g < M) {
                vh = *(const uint4*)&Ahi[(size_t)g * 128 + kc + ko];
                vl = *(const uint4*)&Alo[(size_t)g * 128 + kc + ko];
            }
            *(uint4*)&As_hi[row][ko] = vh;
            *(uint4*)&As_lo[row][ko] = vl;
        }
        #pragma unroll
        for (int i = 0; i < 2; ++i) {
            int row = lr + i * 32;        // n within tile (Nc is a multiple of 64)
            int g = colBase + row;
            uint4 vh = *(const uint4*)&Bhi[(size_t)g * 128 + kc + ko];
            uint4 vl = *(const uint4*)&Blo[(size_t)g * 128 + kc + ko];
            *(uint4*)&Bs_hi[row][ko] = vh;
            *(uint4*)&Bs_lo[row][ko] = vl;
        }
        __syncthreads();

        #pragma unroll
        for (int kq = 0; kq < 2; ++kq) {
            int kof = kq * 32 + quad * 8;
            s16x8 ah[4], al[4], bh[2], bl[2];
            #pragma unroll
            for (int ms = 0; ms < 4; ++ms) {
                int r = mw * 64 + ms * 16 + l15;
                ah[ms] = *(const s16x8*)&As_hi[r][kof];
                al[ms] = *(const s16x8*)&As_lo[r][kof];
            }
            #pragma unroll
            for (int ns = 0; ns < 2; ++ns) {
                int r = nw * 32 + ns * 16 + l15;
                bh[ns] = *(const s16x8*)&Bs_hi[r][kof];
                bl[ns] = *(const s16x8*)&Bs_lo[r][kof];
            }
            #pragma unroll
            for (int ms = 0; ms < 4; ++ms)
                #pragma unroll
                for (int ns = 0; ns < 2; ++ns)
                    acc[ms][ns] = __builtin_amdgcn_mfma_f32_16x16x32_bf16(ah[ms], bh[ns], acc[ms][ns], 0, 0, 0);
            #pragma unroll
            for (int ms = 0; ms < 4; ++ms)
                #pragma unroll
                for (int ns = 0; ns < 2; ++ns)
                    acc[ms][ns] = __builtin_amdgcn_mfma_f32_16x16x32_bf16(al[ms], bh[ns], acc[ms][ns], 0, 0, 0);
            #pragma unroll
            for (int ms = 0; ms < 4; ++ms)
                #pragma unroll
                for (int ns = 0; ns < 2; ++ns)
                    acc[ms][ns] = __builtin_amdgcn_mfma_f32_16x16x32_bf16(ah[ms], bl[ns], acc[ms][ns], 0, 0, 0);
        }
        __syncthreads();
    }

    // epilogue: C/D layout col=lane&15, row=quad*4+reg
    #pragma unroll
    for (int ns = 0; ns < 2; ++ns) {
        int col = colBase + nw * 32 + ns * 16 + l15;
        float bv = bias ? bias[col] : 0.f;
        #pragma unroll
        for (int ms = 0; ms < 4; ++ms) {
            int row0 = rowBase + mw * 64 + ms * 16 + quad * 4;
            #pragma unroll
            for (int r = 0; r < 4; ++r) {
                int row = row0 + r;
                if (row < M) C[(size_t)row * Nc + col] = acc[ms][ns][r] + bv;
            }
        }
    }
}

// ---------------------------------------------------------------- GCN pieces
__global__ void k_self(const float* __restrict__ h, const float* __restrict__ dinv,
                       float* __restrict__ agg) {
    int i = blockIdx.x * 256 + threadIdx.x;   // grid exactly NND*128
    float di = dinv[i >> 7];
    agg[i] = h[i] * di * di;
}

__global__ __launch_bounds__(256) void k_scatter(
    const int* __restrict__ ei, const float* __restrict__ h,
    const float* __restrict__ dinv, float* __restrict__ agg)
{
    int e = blockIdx.x * 2 + (threadIdx.x >> 7);
    int j = threadIdx.x & 127;
    int s = ei[e], d = ei[NE + e];
    float nm = dinv[s] * dinv[d];
    unsafeAtomicAdd(&agg[(size_t)d * 128 + j], h[(size_t)s * 128 + j] * nm);
}

// bias + relu + split-bf16 conversion (output feeds the next MFMA GEMM)
__global__ void k_bias_relu_cvt(const float* __restrict__ agg, const float* __restrict__ b,
                                unsigned short* __restrict__ hi, unsigned short* __restrict__ lo) {
    int i = blockIdx.x * 256 + threadIdx.x;   // grid NND*128/4
    float4 v = ((const float4*)agg)[i];
    float4 bb = *(const float4*)&b[(i * 4) & 127];
    v.x = fmaxf(v.x + bb.x, 0.f);
    v.y = fmaxf(v.y + bb.y, 0.f);
    v.z = fmaxf(v.z + bb.z, 0.f);
    v.w = fmaxf(v.w + bb.w, 0.f);
    ushort4 h, l;
    h.x = f2bf(v.x); l.x = f2bf(v.x - bf2f(h.x));
    h.y = f2bf(v.y); l.y = f2bf(v.y - bf2f(h.y));
    h.z = f2bf(v.z); l.z = f2bf(v.z - bf2f(h.z));
    h.w = f2bf(v.w); l.w = f2bf(v.w - bf2f(h.w));
    ((ushort4*)hi)[i] = h;
    ((ushort4*)lo)[i] = l;
}

// ---------------------------------------------------------------- prep kernels
// GCN weight W [128(k)][128(n)] fp32 -> transposed n-major split-bf16 [n][k]
__global__ void k_prep_gcnw(const float* __restrict__ W,
                            unsigned short* __restrict__ hi, unsigned short* __restrict__ lo) {
    int t = blockIdx.x * 256 + threadIdx.x;
    if (t >= 16384) return;
    int k = t >> 7, n = t & 127;
    float v = W[t];
    unsigned short h = f2bf(v);
    hi[n * 128 + k] = h;
    lo[n * 128 + k] = f2bf(v - bf2f(h));
}

// LSTM prep: both w_ih and w_hh [512(r=g*128+j)][128(k)] -> packed-transposed
// split-bf16 wT[p=j*4+g][k]; bias -> bp[p] = b_ih + b_hh.
__global__ void k_prep_lstm(const float* __restrict__ w_ih, const float* __restrict__ w_hh,
                            const float* __restrict__ b_ih, const float* __restrict__ b_hh,
                            unsigned short* __restrict__ ih_hi, unsigned short* __restrict__ ih_lo,
                            unsigned short* __restrict__ hh_hi, unsigned short* __restrict__ hh_lo,
                            float* __restrict__ bp)
{
    int t = blockIdx.x * 256 + threadIdx.x;
    if (t < 65536) {
        int r = t >> 7, k = t & 127;
        int g = r >> 7, j = r & 127;
        int p = (j << 2) + g;
        float v = w_ih[t];
        unsigned short h = f2bf(v);
        ih_hi[p * 128 + k] = h;
        ih_lo[p * 128 + k] = f2bf(v - bf2f(h));
    } else if (t < 131072) {
        int t2 = t - 65536;
        int r = t2 >> 7, k = t2 & 127;
        int g = r >> 7, j = r & 127;
        int p = (j << 2) + g;
        float v = w_hh[t2];
        unsigned short h = f2bf(v);
        hh_hi[p * 128 + k] = h;
        hh_lo[p * 128 + k] = f2bf(v - bf2f(h));
    } else if (t < 131584) {
        int r = t - 131072;   // 0..511
        int g = r >> 7, j = r & 127;
        bp[(j << 2) + g] = b_ih[r] + b_hh[r];
    }
}

// ---------------------------------------------------------------- LSTM recurrence
// v4.1 (MFMA, stride fix): 512 thr (8 waves), SB=16 sequences/WG, 63 WGs.
// Per step: P[16x512] = h[16x128] @ W_hh^T via split-bf16 16x16x32 MFMA.
// Wave owns 4 n-tiles; weight B-frags (32 x s16x8 = 128 VGPRs) loop-invariant.
// h rows live in LDS at stride AHS=136 shorts (128 k + pad; 16B-aligned).
// P -> LDS part -> phase 2: thread (j=t&127, b=(t>>7)+4q) applies cell,
// c in regs, h written back to LDS as split-bf16 (A operand for next step).
__global__ __launch_bounds__(512, 2) void k_lstm(
    const float* __restrict__ G,            // (NB*TSEQ) x 512, gate-packed cols
    const unsigned short* __restrict__ Whi, // 512 x 128, packed-transposed hi
    const unsigned short* __restrict__ Wlo, // lo
    float* __restrict__ Hout)               // (NB*TSEQ) x 128
{
    const int tid  = threadIdx.x;
    const int lane = tid & 63, wave = tid >> 6;   // 8 waves
    const int l15  = lane & 15, quad = lane >> 4;
    const int b0   = blockIdx.x * SB;

    __shared__ unsigned short Ah[SB * AHS];  // h hi
    __shared__ unsigned short Al[SB * AHS];  // h lo
    __shared__ float part[SB][516];          // P in C/D layout (row=m, col=n)

    // weight fragments: wave owns n-tiles nt0..nt0+3 (n = p = j*4+gate)
    const int nt0 = wave * 4;
    s16x8 bh[4][4], bl[4][4];   // [nt][ks]
    #pragma unroll
    for (int nt = 0; nt < 4; ++nt) {
        int p = (nt0 + nt) * 16 + l15;
        #pragma unroll
        for (int ks = 0; ks < 4; ++ks) {
            bh[nt][ks] = *(const s16x8*)&Whi[(size_t)p * 128 + ks * 32 + quad * 8];
            bl[nt][ks] = *(const s16x8*)&Wlo[(size_t)p * 128 + ks * 32 + quad * 8];
        }
    }

    for (int i = tid; i < SB * AHS; i += 512) { Ah[i] = 0; Al[i] = 0; }

    const int j2 = tid & 127;      // phase-2 hidden unit
    const int bq = tid >> 7;       // phase-2 batch sub-slot (0..3)
    float c[4] = {0.f, 0.f, 0.f, 0.f};
    __syncthreads();

    for (int step = 0; step < TSEQ; ++step) {
        // prefetch gate inputs for phase 2 (independent of phase 1)
        float4 gv[4];
        #pragma unroll
        for (int q = 0; q < 4; ++q) {
            int bg = b0 + bq + q * 4;
            gv[q] = make_float4(0.f, 0.f, 0.f, 0.f);
            if (bg < NB)
                gv[q] = *(const float4*)&G[((size_t)bg * TSEQ + step) * 512 + (j2 << 2)];
        }

        // phase 1: MFMA  P = h @ W^T  (split bf16, lo*lo dropped)
        f32x4 acc[4] = {};
        #pragma unroll
        for (int ks = 0; ks < 4; ++ks) {
            s16x8 ah = *(const s16x8*)&Ah[l15 * AHS + ks * 32 + quad * 8];
            s16x8 al = *(const s16x8*)&Al[l15 * AHS + ks * 32 + quad * 8];
            #pragma unroll
            for (int nt = 0; nt < 4; ++nt) {
                acc[nt] = __builtin_amdgcn_mfma_f32_16x16x32_bf16(ah, bh[nt][ks], acc[nt], 0, 0, 0);
                acc[nt] = __builtin_amdgcn_mfma_f32_16x16x32_bf16(al, bh[nt][ks], acc[nt], 0, 0, 0);
                acc[nt] = __builtin_amdgcn_mfma_f32_16x16x32_bf16(ah, bl[nt][ks], acc[nt], 0, 0, 0);
            }
        }
        // write P to part: row m=quad*4+r, col n=(nt0+nt)*16+l15
        #pragma unroll
        for (int nt = 0; nt < 4; ++nt)
            #pragma unroll
            for (int r = 0; r < 4; ++r)
                part[quad * 4 + r][(nt0 + nt) * 16 + l15] = acc[nt][r];
        __syncthreads();

        // phase 2: LSTM cell for 4 (b, j2) pairs
        #pragma unroll
        for (int q = 0; q < 4; ++q) {
            int b  = bq + q * 4;
            int bg = b0 + b;
            float4 pa = *(const float4*)&part[b][j2 << 2];
            float xi = pa.x + gv[q].x;
            float xf = pa.y + gv[q].y;
            float xg = pa.z + gv[q].z;
            float xo = pa.w + gv[q].w;
            float ii = sigf(xi), ff = sigf(xf), gg = tanhfast(xg), oo = sigf(xo);
            float cn = ff * c[q] + ii * gg;
            c[q] = cn;
            float hn = oo * tanhfast(cn);
            unsigned short hh = f2bf(hn);
            Ah[b * AHS + j2] = hh;
            Al[b * AHS + j2] = f2bf(hn - bf2f(hh));
            if (bg < NB)
                Hout[((size_t)bg * TSEQ + step) * 128 + j2] = hn;
        }
        __syncthreads();
    }
}

// ---------------------------------------------------------------- FC head
__global__ __launch_bounds__(256) void k_fc(
    const float* __restrict__ seq, const float* __restrict__ fcw,
    const float* __restrict__ fcb, float* __restrict__ out)
{
    int b    = blockIdx.x * 4 + (threadIdx.x >> 6);
    int lane = threadIdx.x & 63;
    const float* row = &seq[(((size_t)b) * TSEQ + (TSEQ - 1)) * 128];
    float v = row[lane] * fcw[lane] + row[lane + 64] * fcw[lane + 64];
    #pragma unroll
    for (int off = 32; off > 0; off >>= 1)
        v += __shfl_down(v, off);
    if (lane == 0) out[b] = v + fcb[0];
}

// ---------------------------------------------------------------- launch
extern "C" void kernel_launch(void* const* d_in, const int* in_sizes, int n_in,
                              void* d_out, int out_size, void* d_ws, size_t ws_size,
                              hipStream_t stream)
{
    const float* x    = (const float*)d_in[0];
    const int*   ei   = (const int*)d_in[1];
    const float* W1   = (const float*)d_in[3];
    const float* b1   = (const float*)d_in[4];
    const float* W2   = (const float*)d_in[5];
    const float* b2   = (const float*)d_in[6];
    const float* fcw  = (const float*)d_in[7];
    const float* fcb  = (const float*)d_in[8];
    const float* wih0 = (const float*)d_in[9];
    const float* whh0 = (const float*)d_in[10];
    const float* bih0 = (const float*)d_in[11];
    const float* bhh0 = (const float*)d_in[12];
    const float* wih1 = (const float*)d_in[13];
    const float* whh1 = (const float*)d_in[14];
    const float* bih1 = (const float*)d_in[15];
    const float* bhh1 = (const float*)d_in[16];
    float* out = (float*)d_out;

    char* ws = (char*)d_ws;
    float* bufH = (float*)(ws + 0);           // 25.6 MB fp32 (h pre-agg; later S-hi/lo home)
    float* bufX = (float*)(ws + 25600000);    // 25.6 MB fp32 (agg / seq)
    float* bufG = (float*)(ws + 51200000);    // 102.4 MB fp32 (gates; early: A-hi/lo home)

    // split-bf16 A operands (12.8 MB each). Early phase: in bufG region.
    unsigned short* xhi = (unsigned short*)(ws + 51200000);
    unsigned short* xlo = (unsigned short*)(ws + 64000000);
    // gate-GEMM A operands live in bufH region (bufH free by then)
    unsigned short* shi = (unsigned short*)(ws + 0);
    unsigned short* slo = (unsigned short*)(ws + 12800000);

    float* dinv = (float*)(ws + 153600000);
    float* bp0  = (float*)(ws + 153800192);
    float* bp1  = (float*)(ws + 153802240);
    unsigned short* w1t_hi   = (unsigned short*)(ws + 153804288);
    unsigned short* w1t_lo   = (unsigned short*)(ws + 153837056);
    unsigned short* w2t_hi   = (unsigned short*)(ws + 153869824);
    unsigned short* w2t_lo   = (unsigned short*)(ws + 153902592);
    unsigned short* wpih0_hi = (unsigned short*)(ws + 153935360);
    unsigned short* wpih0_lo = (unsigned short*)(ws + 154066432);
    unsigned short* wpih1_hi = (unsigned short*)(ws + 154197504);
    unsigned short* wpih1_lo = (unsigned short*)(ws + 154328576);
    unsigned short* wphh0_hi = (unsigned short*)(ws + 154459648);
    unsigned short* wphh0_lo = (unsigned short*)(ws + 154590720);
    unsigned short* wphh1_hi = (unsigned short*)(ws + 154721792);
    unsigned short* wphh1_lo = (unsigned short*)(ws + 154852864);

    // degree -> dinv
    hipMemsetAsync(dinv, 0, NND * sizeof(float), stream);
    k_deg<<<(NE + 255) / 256, 256, 0, stream>>>(ei, dinv);
    k_dinv<<<(NND + 255) / 256, 256, 0, stream>>>(dinv);

    // weight prep
    k_prep_gcnw<<<64, 256, 0, stream>>>(W1, w1t_hi, w1t_lo);
    k_prep_gcnw<<<64, 256, 0, stream>>>(W2, w2t_hi, w2t_lo);
    k_prep_lstm<<<514, 256, 0, stream>>>(wih0, whh0, bih0, bhh0,
                                         wpih0_hi, wpih0_lo, wphh0_hi, wphh0_lo, bp0);
    k_prep_lstm<<<514, 256, 0, stream>>>(wih1, whh1, bih1, bhh1,
                                         wpih1_hi, wpih1_lo, wphh1_hi, wphh1_lo, bp1);

    dim3 gH(391, 2);   // 128-col GEMMs (ceil(50000/128)=391)
    dim3 gG(391, 8);   // 512-col GEMMs

    // GCN layer 1
    k_cvt<<<6250, 256, 0, stream>>>(x, xhi, xlo, NND * 128 / 4);
    k_gemm_mfma<<<gH, 256, 0, stream>>>(xhi, xlo, w1t_hi, w1t_lo, nullptr, bufH, NND, 128);
    k_self<<<NND * 128 / 256, 256, 0, stream>>>(bufH, dinv, bufX);
    k_scatter<<<NE / 2, 256, 0, stream>>>(ei, bufH, dinv, bufX);
    k_bias_relu_cvt<<<NND * 128 / 1024, 256, 0, stream>>>(bufX, b1, xhi, xlo);

    // GCN layer 2
    k_gemm_mfma<<<gH, 256, 0, stream>>>(xhi, xlo, w2t_hi, w2t_lo, nullptr, bufH, NND, 128);
    k_self<<<NND * 128 / 256, 256, 0, stream>>>(bufH, dinv, bufX);
    k_scatter<<<NE / 2, 256, 0, stream>>>(ei, bufH, dinv, bufX);
    // relu output -> bufH region (h2 dead after scatter); feeds gate GEMM 0
    k_bias_relu_cvt<<<NND * 128 / 1024, 256, 0, stream>>>(bufX, b2, shi, slo);

    // LSTM layer 0: gate GEMM (bf16 MFMA) + MFMA recurrence
    k_gemm_mfma<<<gG, 256, 0, stream>>>(shi, slo, wpih0_hi, wpih0_lo, bp0, bufG, NND, 512);
    k_lstm<<<(NB + SB - 1) / SB, 512, 0, stream>>>(bufG, wphh0_hi, wphh0_lo, bufX);  // seq0 -> bufX

    // LSTM layer 1
    k_cvt<<<6250, 256, 0, stream>>>(bufX, shi, slo, NND * 128 / 4);
    k_gemm_mfma<<<gG, 256, 0, stream>>>(shi, slo, wpih1_hi, wpih1_lo, bp1, bufG, NND, 512);
    k_lstm<<<(NB + SB - 1) / SB, 512, 0, stream>>>(bufG, wphh1_hi, wphh1_lo, bufX);  // seq1 -> bufX

    // FC head
    k_fc<<<NB / 4, 256, 0, stream>>>(bufX, fcw, fcb, out);
}

// Round 8
// 875.375 us; speedup vs baseline: 1.6856x; 1.3391x over previous
//
#include <hip/hip_runtime.h>

// Problem constants (fixed by the reference file)
#define NND 50000   // nodes
#define NE  600000  // edges
#define TSEQ 50     // sequence length
#define NB  1000    // batch = NND/TSEQ
#define SB  16      // sequences per LSTM workgroup
#define AHS 136     // LDS h-row stride in shorts (128 + 8 pad, 16B-aligned)

typedef __attribute__((ext_vector_type(4))) float f32x4;
typedef __attribute__((ext_vector_type(8))) short s16x8;

// ---------------------------------------------------------------- helpers
__device__ __forceinline__ float sigf(float x) {
    return 1.0f / (1.0f + __expf(-x));
}
__device__ __forceinline__ float tanhfast(float x) {
    x = fminf(fmaxf(x, -15.f), 15.f);
    float e = __expf(2.f * x);
    return (e - 1.f) / (e + 1.f);
}
// bf16 bit helpers (round-to-nearest-even)
__device__ __forceinline__ unsigned short f2bf(float f) {
    unsigned int u = __float_as_uint(f);
    u = u + 0x7FFFu + ((u >> 16) & 1u);
    return (unsigned short)(u >> 16);
}
__device__ __forceinline__ float bf2f(unsigned short h) {
    return __uint_as_float(((unsigned int)h) << 16);
}

// ---------------------------------------------------------------- CSR build
__global__ void k_count(const int* __restrict__ ei, int* __restrict__ cnt) {
    int e = blockIdx.x * 256 + threadIdx.x;
    if (e < NE) atomicAdd(&cnt[ei[NE + e]], 1);
}

__global__ void k_dinv(const int* __restrict__ cnt, float* __restrict__ dinv) {
    int i = blockIdx.x * 256 + threadIdx.x;
    if (i < NND) dinv[i] = 1.0f / sqrtf((float)cnt[i] + 1.0f);
}

// single-WG exclusive scan of cnt -> rowstart (rowstart[NND] = NE)
__global__ __launch_bounds__(1024) void k_scan(const int* __restrict__ cnt,
                                               int* __restrict__ rowstart) {
    __shared__ int ps[1024];
    const int t = threadIdx.x;
    const int CH = (NND + 1023) / 1024;   // 49
    int base = t * CH;
    int s = 0;
    for (int i = 0; i < CH; ++i) {
        int idx = base + i;
        if (idx < NND) s += cnt[idx];
    }
    ps[t] = s;
    __syncthreads();
    for (int off = 1; off < 1024; off <<= 1) {
        int v = 0;
        if (t >= off) v = ps[t - off];
        __syncthreads();
        if (t >= off) ps[t] += v;
        __syncthreads();
    }
    int run = (t == 0) ? 0 : ps[t - 1];
    for (int i = 0; i < CH; ++i) {
        int idx = base + i;
        if (idx < NND) { rowstart[idx] = run; run += cnt[idx]; }
    }
    if (t == 1023) rowstart[NND] = ps[1023];
}

__global__ void k_fill(const int* __restrict__ ei, const int* __restrict__ rowstart,
                       int* __restrict__ cursor, int* __restrict__ adj) {
    int e = blockIdx.x * 256 + threadIdx.x;
    if (e >= NE) return;
    int s = ei[e], d = ei[NE + e];
    int pos = atomicAdd(&cursor[d], 1);
    adj[rowstart[d] + pos] = s;
}

// ---------------------------------------------------------------- cvt fp32 -> split bf16
__global__ void k_cvt(const float* __restrict__ in, unsigned short* __restrict__ hi,
                      unsigned short* __restrict__ lo, int n4) {
    int i = blockIdx.x * 256 + threadIdx.x;
    if (i >= n4) return;
    float4 v = ((const float4*)in)[i];
    ushort4 h, l;
    h.x = f2bf(v.x); l.x = f2bf(v.x - bf2f(h.x));
    h.y = f2bf(v.y); l.y = f2bf(v.y - bf2f(h.y));
    h.z = f2bf(v.z); l.z = f2bf(v.z - bf2f(h.z));
    h.w = f2bf(v.w); l.w = f2bf(v.w - bf2f(h.w));
    ((ushort4*)hi)[i] = h;
    ((ushort4*)lo)[i] = l;
}

// ---------------------------------------------------------------- MFMA GEMM
// C[M x Nc] = A[M x 128] @ B[128 x Nc] + bias, split-bf16 (3 MFMAs / tile).
// A given as hi/lo bf16 [M][128]; B given TRANSPOSED n-major hi/lo [Nc][128].
// 256 thr, tile 128x64, 4 waves: wave = (mw = w&1 -> 64 rows, nw = w>>1 -> 32 cols).
__global__ __launch_bounds__(256) void k_gemm_mfma(
    const unsigned short* __restrict__ Ahi, const unsigned short* __restrict__ Alo,
    const unsigned short* __restrict__ Bhi, const unsigned short* __restrict__ Blo,
    const float* __restrict__ bias, float* __restrict__ C,
    int M, int Nc)
{
    __shared__ unsigned short As_hi[128][72];
    __shared__ unsigned short As_lo[128][72];
    __shared__ unsigned short Bs_hi[64][72];
    __shared__ unsigned short Bs_lo[64][72];

    const int tid  = threadIdx.x;
    const int lane = tid & 63, wave = tid >> 6;
    const int mw = wave & 1, nw = wave >> 1;
    const int l15 = lane & 15, quad = lane >> 4;
    const int rowBase = blockIdx.x * 128;
    const int colBase = blockIdx.y * 64;

    f32x4 acc[4][2] = {};

    for (int kc = 0; kc < 128; kc += 64) {
        // stage A (128 rows x 64 k) and B (64 n-rows x 64 k), 16B copies
        int lr = tid >> 3;            // 0..31
        int ko = (tid & 7) * 8;       // 0..56
        #pragma unroll
        for (int i = 0; i < 4; ++i) {
            int row = lr + i * 32;
            int g = rowBase + row;
            uint4 vh = make_uint4(0, 0, 0, 0), vl = make_uint4(0, 0, 0, 0);
            if (g < M) {
                vh = *(const uint4*)&Ahi[(size_t)g * 128 + kc + ko];
                vl = *(const uint4*)&Alo[(size_t)g * 128 + kc + ko];
            }
            *(uint4*)&As_hi[row][ko] = vh;
            *(uint4*)&As_lo[row][ko] = vl;
        }
        #pragma unroll
        for (int i = 0; i < 2; ++i) {
            int row = lr + i * 32;        // n within tile (Nc is a multiple of 64)
            int g = colBase + row;
            uint4 vh = *(const uint4*)&Bhi[(size_t)g * 128 + kc + ko];
            uint4 vl = *(const uint4*)&Blo[(size_t)g * 128 + kc + ko];
            *(uint4*)&Bs_hi[row][ko] = vh;
            *(uint4*)&Bs_lo[row][ko] = vl;
        }
        __syncthreads();

        #pragma unroll
        for (int kq = 0; kq < 2; ++kq) {
            int kof = kq * 32 + quad * 8;
            s16x8 ah[4], al[4], bh[2], bl[2];
            #pragma unroll
            for (int ms = 0; ms < 4; ++ms) {
                int r = mw * 64 + ms * 16 + l15;
                ah[ms] = *(const s16x8*)&As_hi[r][kof];
                al[ms] = *(const s16x8*)&As_lo[r][kof];
            }
            #pragma unroll
            for (int ns = 0; ns < 2; ++ns) {
                int r = nw * 32 + ns * 16 + l15;
                bh[ns] = *(const s16x8*)&Bs_hi[r][kof];
                bl[ns] = *(const s16x8*)&Bs_lo[r][kof];
            }
            #pragma unroll
            for (int ms = 0; ms < 4; ++ms)
                #pragma unroll
                for (int ns = 0; ns < 2; ++ns)
                    acc[ms][ns] = __builtin_amdgcn_mfma_f32_16x16x32_bf16(ah[ms], bh[ns], acc[ms][ns], 0, 0, 0);
            #pragma unroll
            for (int ms = 0; ms < 4; ++ms)
                #pragma unroll
                for (int ns = 0; ns < 2; ++ns)
                    acc[ms][ns] = __builtin_amdgcn_mfma_f32_16x16x32_bf16(al[ms], bh[ns], acc[ms][ns], 0, 0, 0);
            #pragma unroll
            for (int ms = 0; ms < 4; ++ms)
                #pragma unroll
                for (int ns = 0; ns < 2; ++ns)
                    acc[ms][ns] = __builtin_amdgcn_mfma_f32_16x16x32_bf16(ah[ms], bl[ns], acc[ms][ns], 0, 0, 0);
        }
        __syncthreads();
    }

    // epilogue: C/D layout col=lane&15, row=quad*4+reg
    #pragma unroll
    for (int ns = 0; ns < 2; ++ns) {
        int col = colBase + nw * 32 + ns * 16 + l15;
        float bv = bias ? bias[col] : 0.f;
        #pragma unroll
        for (int ms = 0; ms < 4; ++ms) {
            int row0 = rowBase + mw * 64 + ms * 16 + quad * 4;
            #pragma unroll
            for (int r = 0; r < 4; ++r) {
                int row = row0 + r;
                if (row < M) C[(size_t)row * Nc + col] = acc[ms][ns][r] + bv;
            }
        }
    }
}

// ---------------------------------------------------------------- GCN gather
// One wave per node; lane owns 2 cols (float2). agg = dn*(sum_s h[s]*ds + h[n]*dn),
// fused bias + relu + split-bf16 output (feeds the next MFMA GEMM directly).
// NOTE: hi/lo output MUST NOT alias h (blocks read arbitrary h rows).
__global__ __launch_bounds__(256) void k_gather(
    const int* __restrict__ rowstart, const int* __restrict__ adj,
    const float* __restrict__ h, const float* __restrict__ dinv,
    const float* __restrict__ bias,
    unsigned short* __restrict__ hi, unsigned short* __restrict__ lo)
{
    const int n    = blockIdx.x * 4 + (threadIdx.x >> 6);   // grid exactly NND/4
    const int lane = threadIdx.x & 63;
    const int r0 = rowstart[n], r1 = rowstart[n + 1];
    const float dn = dinv[n];

    float2 hv = *(const float2*)&h[(size_t)n * 128 + 2 * lane];
    float2 acc;
    acc.x = hv.x * dn;
    acc.y = hv.y * dn;
    for (int i = r0; i < r1; ++i) {
        int s = adj[i];                 // wave-uniform broadcast
        float ds = dinv[s];
        float2 v = *(const float2*)&h[(size_t)s * 128 + 2 * lane];
        acc.x += v.x * ds;
        acc.y += v.y * ds;
    }
    float2 bb = *(const float2*)&bias[2 * lane];
    float vx = fmaxf(acc.x * dn + bb.x, 0.f);
    float vy = fmaxf(acc.y * dn + bb.y, 0.f);
    ushort2 ho, lo2;
    ho.x = f2bf(vx); lo2.x = f2bf(vx - bf2f(ho.x));
    ho.y = f2bf(vy); lo2.y = f2bf(vy - bf2f(ho.y));
    *(ushort2*)&hi[(size_t)n * 128 + 2 * lane] = ho;
    *(ushort2*)&lo[(size_t)n * 128 + 2 * lane] = lo2;
}

// ---------------------------------------------------------------- prep kernels
// GCN weight W [128(k)][128(n)] fp32 -> transposed n-major split-bf16 [n][k]
__global__ void k_prep_gcnw(const float* __restrict__ W,
                            unsigned short* __restrict__ hi, unsigned short* __restrict__ lo) {
    int t = blockIdx.x * 256 + threadIdx.x;
    if (t >= 16384) return;
    int k = t >> 7, n = t & 127;
    float v = W[t];
    unsigned short h = f2bf(v);
    hi[n * 128 + k] = h;
    lo[n * 128 + k] = f2bf(v - bf2f(h));
}

// LSTM prep: both w_ih and w_hh [512(r=g*128+j)][128(k)] -> packed-transposed
// split-bf16 wT[p=j*4+g][k]; bias -> bp[p] = b_ih + b_hh.
__global__ void k_prep_lstm(const float* __restrict__ w_ih, const float* __restrict__ w_hh,
                            const float* __restrict__ b_ih, const float* __restrict__ b_hh,
                            unsigned short* __restrict__ ih_hi, unsigned short* __restrict__ ih_lo,
                            unsigned short* __restrict__ hh_hi, unsigned short* __restrict__ hh_lo,
                            float* __restrict__ bp)
{
    int t = blockIdx.x * 256 + threadIdx.x;
    if (t < 65536) {
        int r = t >> 7, k = t & 127;
        int g = r >> 7, j = r & 127;
        int p = (j << 2) + g;
        float v = w_ih[t];
        unsigned short h = f2bf(v);
        ih_hi[p * 128 + k] = h;
        ih_lo[p * 128 + k] = f2bf(v - bf2f(h));
    } else if (t < 131072) {
        int t2 = t - 65536;
        int r = t2 >> 7, k = t2 & 127;
        int g = r >> 7, j = r & 127;
        int p = (j << 2) + g;
        float v = w_hh[t2];
        unsigned short h = f2bf(v);
        hh_hi[p * 128 + k] = h;
        hh_lo[p * 128 + k] = f2bf(v - bf2f(h));
    } else if (t < 131584) {
        int r = t - 131072;   // 0..511
        int g = r >> 7, j = r & 127;
        bp[(j << 2) + g] = b_ih[r] + b_hh[r];
    }
}

// ---------------------------------------------------------------- LSTM recurrence
// v4.1 (MFMA): 512 thr (8 waves), SB=16 sequences/WG, 63 WGs.
// Per step: P[16x512] = h[16x128] @ W_hh^T via split-bf16 16x16x32 MFMA.
// Wave owns 4 n-tiles; weight B-frags loop-invariant in VGPRs.
// h rows live in LDS at stride AHS=136 shorts (128 k + pad; 16B-aligned).
__global__ __launch_bounds__(512, 2) void k_lstm(
    const float* __restrict__ G,            // (NB*TSEQ) x 512, gate-packed cols
    const unsigned short* __restrict__ Whi, // 512 x 128, packed-transposed hi
    const unsigned short* __restrict__ Wlo, // lo
    float* __restrict__ Hout)               // (NB*TSEQ) x 128
{
    const int tid  = threadIdx.x;
    const int lane = tid & 63, wave = tid >> 6;   // 8 waves
    const int l15  = lane & 15, quad = lane >> 4;
    const int b0   = blockIdx.x * SB;

    __shared__ unsigned short Ah[SB * AHS];  // h hi
    __shared__ unsigned short Al[SB * AHS];  // h lo
    __shared__ float part[SB][516];          // P in C/D layout (row=m, col=n)

    // weight fragments: wave owns n-tiles nt0..nt0+3 (n = p = j*4+gate)
    const int nt0 = wave * 4;
    s16x8 bh[4][4], bl[4][4];   // [nt][ks]
    #pragma unroll
    for (int nt = 0; nt < 4; ++nt) {
        int p = (nt0 + nt) * 16 + l15;
        #pragma unroll
        for (int ks = 0; ks < 4; ++ks) {
            bh[nt][ks] = *(const s16x8*)&Whi[(size_t)p * 128 + ks * 32 + quad * 8];
            bl[nt][ks] = *(const s16x8*)&Wlo[(size_t)p * 128 + ks * 32 + quad * 8];
        }
    }

    for (int i = tid; i < SB * AHS; i += 512) { Ah[i] = 0; Al[i] = 0; }

    const int j2 = tid & 127;      // phase-2 hidden unit
    const int bq = tid >> 7;       // phase-2 batch sub-slot (0..3)
    float c[4] = {0.f, 0.f, 0.f, 0.f};
    __syncthreads();

    for (int step = 0; step < TSEQ; ++step) {
        // prefetch gate inputs for phase 2 (independent of phase 1)
        float4 gv[4];
        #pragma unroll
        for (int q = 0; q < 4; ++q) {
            int bg = b0 + bq + q * 4;
            gv[q] = make_float4(0.f, 0.f, 0.f, 0.f);
            if (bg < NB)
                gv[q] = *(const float4*)&G[((size_t)bg * TSEQ + step) * 512 + (j2 << 2)];
        }

        // phase 1: MFMA  P = h @ W^T  (split bf16, lo*lo dropped)
        f32x4 acc[4] = {};
        #pragma unroll
        for (int ks = 0; ks < 4; ++ks) {
            s16x8 ah = *(const s16x8*)&Ah[l15 * AHS + ks * 32 + quad * 8];
            s16x8 al = *(const s16x8*)&Al[l15 * AHS + ks * 32 + quad * 8];
            #pragma unroll
            for (int nt = 0; nt < 4; ++nt) {
                acc[nt] = __builtin_amdgcn_mfma_f32_16x16x32_bf16(ah, bh[nt][ks], acc[nt], 0, 0, 0);
                acc[nt] = __builtin_amdgcn_mfma_f32_16x16x32_bf16(al, bh[nt][ks], acc[nt], 0, 0, 0);
                acc[nt] = __builtin_amdgcn_mfma_f32_16x16x32_bf16(ah, bl[nt][ks], acc[nt], 0, 0, 0);
            }
        }
        // write P to part: row m=quad*4+r, col n=(nt0+nt)*16+l15
        #pragma unroll
        for (int nt = 0; nt < 4; ++nt)
            #pragma unroll
            for (int r = 0; r < 4; ++r)
                part[quad * 4 + r][(nt0 + nt) * 16 + l15] = acc[nt][r];
        __syncthreads();

        // phase 2: LSTM cell for 4 (b, j2) pairs
        #pragma unroll
        for (int q = 0; q < 4; ++q) {
            int b  = bq + q * 4;
            int bg = b0 + b;
            float4 pa = *(const float4*)&part[b][j2 << 2];
            float xi = pa.x + gv[q].x;
            float xf = pa.y + gv[q].y;
            float xg = pa.z + gv[q].z;
            float xo = pa.w + gv[q].w;
            float ii = sigf(xi), ff = sigf(xf), gg = tanhfast(xg), oo = sigf(xo);
            float cn = ff * c[q] + ii * gg;
            c[q] = cn;
            float hn = oo * tanhfast(cn);
            unsigned short hh = f2bf(hn);
            Ah[b * AHS + j2] = hh;
            Al[b * AHS + j2] = f2bf(hn - bf2f(hh));
            if (bg < NB)
                Hout[((size_t)bg * TSEQ + step) * 128 + j2] = hn;
        }
        __syncthreads();
    }
}

// ---------------------------------------------------------------- FC head
__global__ __launch_bounds__(256) void k_fc(
    const float* __restrict__ seq, const float* __restrict__ fcw,
    const float* __restrict__ fcb, float* __restrict__ out)
{
    int b    = blockIdx.x * 4 + (threadIdx.x >> 6);
    int lane = threadIdx.x & 63;
    const float* row = &seq[(((size_t)b) * TSEQ + (TSEQ - 1)) * 128];
    float v = row[lane] * fcw[lane] + row[lane + 64] * fcw[lane + 64];
    #pragma unroll
    for (int off = 32; off > 0; off >>= 1)
        v += __shfl_down(v, off);
    if (lane == 0) out[b] = v + fcb[0];
}

// ---------------------------------------------------------------- launch
extern "C" void kernel_launch(void* const* d_in, const int* in_sizes, int n_in,
                              void* d_out, int out_size, void* d_ws, size_t ws_size,
                              hipStream_t stream)
{
    const float* x    = (const float*)d_in[0];
    const int*   ei   = (const int*)d_in[1];
    const float* W1   = (const float*)d_in[3];
    const float* b1   = (const float*)d_in[4];
    const float* W2   = (const float*)d_in[5];
    const float* b2   = (const float*)d_in[6];
    const float* fcw  = (const float*)d_in[7];
    const float* fcb  = (const float*)d_in[8];
    const float* wih0 = (const float*)d_in[9];
    const float* whh0 = (const float*)d_in[10];
    const float* bih0 = (const float*)d_in[11];
    const float* bhh0 = (const float*)d_in[12];
    const float* wih1 = (const float*)d_in[13];
    const float* whh1 = (const float*)d_in[14];
    const float* bih1 = (const float*)d_in[15];
    const float* bhh1 = (const float*)d_in[16];
    float* out = (float*)d_out;

    char* ws = (char*)d_ws;
    // ---- persistent regions
    unsigned short* shi = (unsigned short*)(ws + 0);          // 12.8 MB
    unsigned short* slo = (unsigned short*)(ws + 12800000);   // 12.8 MB (ends 25.6M)
    float* bufX = (float*)(ws + 25600000);                    // 25.6 MB (ends 51.2M)
    float* bufG = (float*)(ws + 51200000);                    // 102.4 MB (ends 153.6M)

    // ---- GCN-phase regions (inside bufG, dead before gate GEMM writes bufG)
    unsigned short* xhi = (unsigned short*)(ws + 51200000);   // 12.8 MB
    unsigned short* xlo = (unsigned short*)(ws + 64000000);   // 12.8 MB
    float* bufHg  = (float*)(ws + 76800000);                  // 25.6 MB (ends 102.4M)
    int* cnt      = (int*)(ws + 102400000);
    int* rowstart = (int*)(ws + 102604800);
    int* cursor   = (int*)(ws + 102809600);
    int* adj      = (int*)(ws + 103014400);                   // 2.4 MB (ends 105.42M)

    float* dinv = (float*)(ws + 153600000);
    float* bp0  = (float*)(ws + 153800192);
    float* bp1  = (float*)(ws + 153802240);
    unsigned short* w1t_hi   = (unsigned short*)(ws + 153804288);
    unsigned short* w1t_lo   = (unsigned short*)(ws + 153837056);
    unsigned short* w2t_hi   = (unsigned short*)(ws + 153869824);
    unsigned short* w2t_lo   = (unsigned short*)(ws + 153902592);
    unsigned short* wpih0_hi = (unsigned short*)(ws + 153935360);
    unsigned short* wpih0_lo = (unsigned short*)(ws + 154066432);
    unsigned short* wpih1_hi = (unsigned short*)(ws + 154197504);
    unsigned short* wpih1_lo = (unsigned short*)(ws + 154328576);
    unsigned short* wphh0_hi = (unsigned short*)(ws + 154459648);
    unsigned short* wphh0_lo = (unsigned short*)(ws + 154590720);
    unsigned short* wphh1_hi = (unsigned short*)(ws + 154721792);
    unsigned short* wphh1_lo = (unsigned short*)(ws + 154852864);

    // ---- CSR build + dinv
    hipMemsetAsync(cnt, 0, NND * sizeof(int), stream);
    hipMemsetAsync(cursor, 0, NND * sizeof(int), stream);
    k_count<<<(NE + 255) / 256, 256, 0, stream>>>(ei, cnt);
    k_scan<<<1, 1024, 0, stream>>>(cnt, rowstart);
    k_dinv<<<(NND + 255) / 256, 256, 0, stream>>>(cnt, dinv);
    k_fill<<<(NE + 255) / 256, 256, 0, stream>>>(ei, rowstart, cursor, adj);

    // ---- weight prep
    k_prep_gcnw<<<64, 256, 0, stream>>>(W1, w1t_hi, w1t_lo);
    k_prep_gcnw<<<64, 256, 0, stream>>>(W2, w2t_hi, w2t_lo);
    k_prep_lstm<<<514, 256, 0, stream>>>(wih0, whh0, bih0, bhh0,
                                         wpih0_hi, wpih0_lo, wphh0_hi, wphh0_lo, bp0);
    k_prep_lstm<<<514, 256, 0, stream>>>(wih1, whh1, bih1, bhh1,
                                         wpih1_hi, wpih1_lo, wphh1_hi, wphh1_lo, bp1);

    dim3 gH(391, 2);   // 128-col GEMMs (ceil(50000/128)=391)
    dim3 gG(391, 8);   // 512-col GEMMs

    // ---- GCN layer 1  (reads 51.2-76.8M, writes 76.8-102.4M; then gather
    //      reads 76.8-102.4M, writes 51.2-76.8M — disjoint at every step)
    k_cvt<<<6250, 256, 0, stream>>>(x, xhi, xlo, NND * 128 / 4);
    k_gemm_mfma<<<gH, 256, 0, stream>>>(xhi, xlo, w1t_hi, w1t_lo, nullptr, bufHg, NND, 128);
    k_gather<<<NND / 4, 256, 0, stream>>>(rowstart, adj, bufHg, dinv, b1, xhi, xlo);

    // ---- GCN layer 2 (gather writes shi/slo @0-25.6M, disjoint from bufHg)
    k_gemm_mfma<<<gH, 256, 0, stream>>>(xhi, xlo, w2t_hi, w2t_lo, nullptr, bufHg, NND, 128);
    k_gather<<<NND / 4, 256, 0, stream>>>(rowstart, adj, bufHg, dinv, b2, shi, slo);

    // ---- LSTM layer 0: gate GEMM (bf16 MFMA) + MFMA recurrence
    k_gemm_mfma<<<gG, 256, 0, stream>>>(shi, slo, wpih0_hi, wpih0_lo, bp0, bufG, NND, 512);
    k_lstm<<<(NB + SB - 1) / SB, 512, 0, stream>>>(bufG, wphh0_hi, wphh0_lo, bufX);  // seq0 -> bufX

    // ---- LSTM layer 1
    k_cvt<<<6250, 256, 0, stream>>>(bufX, shi, slo, NND * 128 / 4);
    k_gemm_mfma<<<gG, 256, 0, stream>>>(shi, slo, wpih1_hi, wpih1_lo, bp1, bufG, NND, 512);
    k_lstm<<<(NB + SB - 1) / SB, 512, 0, stream>>>(bufG, wphh1_hi, wphh1_lo, bufX);  // seq1 -> bufX

    // ---- FC head
    k_fc<<<NB / 4, 256, 0, stream>>>(bufX, fcw, fcb, out);
}

// Round 9
// 750.238 us; speedup vs baseline: 1.9667x; 1.1668x over previous
//
#include <hip/hip_runtime.h>

// Problem constants (fixed by the reference file)
#define NND 50000   // nodes
#define NE  600000  // edges
#define TSEQ 50     // sequence length
#define NB  1000    // batch = NND/TSEQ
#define SB  4       // sequences per LSTM workgroup (250 WGs ~= 1/CU)
#define AHS 136     // LDS h-row stride in shorts (128 + 8 pad, 16B-aligned)

typedef __attribute__((ext_vector_type(4))) float f32x4;
typedef __attribute__((ext_vector_type(8))) short s16x8;

// ---------------------------------------------------------------- helpers
__device__ __forceinline__ float sigf(float x) {
    return 1.0f / (1.0f + __expf(-x));
}
__device__ __forceinline__ float tanhfast(float x) {
    x = fminf(fmaxf(x, -15.f), 15.f);
    float e = __expf(2.f * x);
    return (e - 1.f) / (e + 1.f);
}
// bf16 bit helpers (round-to-nearest-even)
__device__ __forceinline__ unsigned short f2bf(float f) {
    unsigned int u = __float_as_uint(f);
    u = u + 0x7FFFu + ((u >> 16) & 1u);
    return (unsigned short)(u >> 16);
}
__device__ __forceinline__ float bf2f(unsigned short h) {
    return __uint_as_float(((unsigned int)h) << 16);
}

// ---------------------------------------------------------------- CSR build
__global__ void k_count(const int* __restrict__ ei, int* __restrict__ cnt) {
    int e = blockIdx.x * 256 + threadIdx.x;
    if (e < NE) atomicAdd(&cnt[ei[NE + e]], 1);
}

__global__ void k_dinv(const int* __restrict__ cnt, float* __restrict__ dinv) {
    int i = blockIdx.x * 256 + threadIdx.x;
    if (i < NND) dinv[i] = 1.0f / sqrtf((float)cnt[i] + 1.0f);
}

// single-WG exclusive scan of cnt -> rowstart (rowstart[NND] = NE)
__global__ __launch_bounds__(1024) void k_scan(const int* __restrict__ cnt,
                                               int* __restrict__ rowstart) {
    __shared__ int ps[1024];
    const int t = threadIdx.x;
    const int CH = (NND + 1023) / 1024;   // 49
    int base = t * CH;
    int s = 0;
    for (int i = 0; i < CH; ++i) {
        int idx = base + i;
        if (idx < NND) s += cnt[idx];
    }
    ps[t] = s;
    __syncthreads();
    for (int off = 1; off < 1024; off <<= 1) {
        int v = 0;
        if (t >= off) v = ps[t - off];
        __syncthreads();
        if (t >= off) ps[t] += v;
        __syncthreads();
    }
    int run = (t == 0) ? 0 : ps[t - 1];
    for (int i = 0; i < CH; ++i) {
        int idx = base + i;
        if (idx < NND) { rowstart[idx] = run; run += cnt[idx]; }
    }
    if (t == 1023) rowstart[NND] = ps[1023];
}

__global__ void k_fill(const int* __restrict__ ei, const int* __restrict__ rowstart,
                       int* __restrict__ cursor, int* __restrict__ adj) {
    int e = blockIdx.x * 256 + threadIdx.x;
    if (e >= NE) return;
    int s = ei[e], d = ei[NE + e];
    int pos = atomicAdd(&cursor[d], 1);
    adj[rowstart[d] + pos] = s;
}

// ---------------------------------------------------------------- cvt fp32 -> split bf16
__global__ void k_cvt(const float* __restrict__ in, unsigned short* __restrict__ hi,
                      unsigned short* __restrict__ lo, int n4) {
    int i = blockIdx.x * 256 + threadIdx.x;
    if (i >= n4) return;
    float4 v = ((const float4*)in)[i];
    ushort4 h, l;
    h.x = f2bf(v.x); l.x = f2bf(v.x - bf2f(h.x));
    h.y = f2bf(v.y); l.y = f2bf(v.y - bf2f(h.y));
    h.z = f2bf(v.z); l.z = f2bf(v.z - bf2f(h.z));
    h.w = f2bf(v.w); l.w = f2bf(v.w - bf2f(h.w));
    ((ushort4*)hi)[i] = h;
    ((ushort4*)lo)[i] = l;
}

// ---------------------------------------------------------------- MFMA GEMM
// C[M x Nc] = A[M x 128] @ B[128 x Nc] + bias, split-bf16 (3 MFMAs / tile).
// A given as hi/lo bf16 [M][128]; B given TRANSPOSED n-major hi/lo [Nc][128].
// 256 thr, tile 128x64, 4 waves: wave = (mw = w&1 -> 64 rows, nw = w>>1 -> 32 cols).
__global__ __launch_bounds__(256) void k_gemm_mfma(
    const unsigned short* __restrict__ Ahi, const unsigned short* __restrict__ Alo,
    const unsigned short* __restrict__ Bhi, const unsigned short* __restrict__ Blo,
    const float* __restrict__ bias, float* __restrict__ C,
    int M, int Nc)
{
    __shared__ unsigned short As_hi[128][72];
    __shared__ unsigned short As_lo[128][72];
    __shared__ unsigned short Bs_hi[64][72];
    __shared__ unsigned short Bs_lo[64][72];

    const int tid  = threadIdx.x;
    const int lane = tid & 63, wave = tid >> 6;
    const int mw = wave & 1, nw = wave >> 1;
    const int l15 = lane & 15, quad = lane >> 4;
    const int rowBase = blockIdx.x * 128;
    const int colBase = blockIdx.y * 64;

    f32x4 acc[4][2] = {};

    for (int kc = 0; kc < 128; kc += 64) {
        // stage A (128 rows x 64 k) and B (64 n-rows x 64 k), 16B copies
        int lr = tid >> 3;            // 0..31
        int ko = (tid & 7) * 8;       // 0..56
        #pragma unroll
        for (int i = 0; i < 4; ++i) {
            int row = lr + i * 32;
            int g = rowBase + row;
            uint4 vh = make_uint4(0, 0, 0, 0), vl = make_uint4(0, 0, 0, 0);
            if (g < M) {
                vh = *(const uint4*)&Ahi[(size_t)g * 128 + kc + ko];
                vl = *(const uint4*)&Alo[(size_t)g * 128 + kc + ko];
            }
            *(uint4*)&As_hi[row][ko] = vh;
            *(uint4*)&As_lo[row][ko] = vl;
        }
        #pragma unroll
        for (int i = 0; i < 2; ++i) {
            int row = lr + i * 32;        // n within tile (Nc is a multiple of 64)
            int g = colBase + row;
            uint4 vh = *(const uint4*)&Bhi[(size_t)g * 128 + kc + ko];
            uint4 vl = *(const uint4*)&Blo[(size_t)g * 128 + kc + ko];
            *(uint4*)&Bs_hi[row][ko] = vh;
            *(uint4*)&Bs_lo[row][ko] = vl;
        }
        __syncthreads();

        #pragma unroll
        for (int kq = 0; kq < 2; ++kq) {
            int kof = kq * 32 + quad * 8;
            s16x8 ah[4], al[4], bh[2], bl[2];
            #pragma unroll
            for (int ms = 0; ms < 4; ++ms) {
                int r = mw * 64 + ms * 16 + l15;
                ah[ms] = *(const s16x8*)&As_hi[r][kof];
                al[ms] = *(const s16x8*)&As_lo[r][kof];
            }
            #pragma unroll
            for (int ns = 0; ns < 2; ++ns) {
                int r = nw * 32 + ns * 16 + l15;
                bh[ns] = *(const s16x8*)&Bs_hi[r][kof];
                bl[ns] = *(const s16x8*)&Bs_lo[r][kof];
            }
            #pragma unroll
            for (int ms = 0; ms < 4; ++ms)
                #pragma unroll
                for (int ns = 0; ns < 2; ++ns)
                    acc[ms][ns] = __builtin_amdgcn_mfma_f32_16x16x32_bf16(ah[ms], bh[ns], acc[ms][ns], 0, 0, 0);
            #pragma unroll
            for (int ms = 0; ms < 4; ++ms)
                #pragma unroll
                for (int ns = 0; ns < 2; ++ns)
                    acc[ms][ns] = __builtin_amdgcn_mfma_f32_16x16x32_bf16(al[ms], bh[ns], acc[ms][ns], 0, 0, 0);
            #pragma unroll
            for (int ms = 0; ms < 4; ++ms)
                #pragma unroll
                for (int ns = 0; ns < 2; ++ns)
                    acc[ms][ns] = __builtin_amdgcn_mfma_f32_16x16x32_bf16(ah[ms], bl[ns], acc[ms][ns], 0, 0, 0);
        }
        __syncthreads();
    }

    // epilogue: C/D layout col=lane&15, row=quad*4+reg
    #pragma unroll
    for (int ns = 0; ns < 2; ++ns) {
        int col = colBase + nw * 32 + ns * 16 + l15;
        float bv = bias ? bias[col] : 0.f;
        #pragma unroll
        for (int ms = 0; ms < 4; ++ms) {
            int row0 = rowBase + mw * 64 + ms * 16 + quad * 4;
            #pragma unroll
            for (int r = 0; r < 4; ++r) {
                int row = row0 + r;
                if (row < M) C[(size_t)row * Nc + col] = acc[ms][ns][r] + bv;
            }
        }
    }
}

// ---------------------------------------------------------------- GCN gather
// One wave per node; lane owns 2 cols (float2). agg = dn*(sum_s h[s]*ds + h[n]*dn),
// fused bias + relu + split-bf16 output (feeds the next MFMA GEMM directly).
// NOTE: hi/lo output MUST NOT alias h (blocks read arbitrary h rows).
__global__ __launch_bounds__(256) void k_gather(
    const int* __restrict__ rowstart, const int* __restrict__ adj,
    const float* __restrict__ h, const float* __restrict__ dinv,
    const float* __restrict__ bias,
    unsigned short* __restrict__ hi, unsigned short* __restrict__ lo)
{
    const int n    = blockIdx.x * 4 + (threadIdx.x >> 6);   // grid exactly NND/4
    const int lane = threadIdx.x & 63;
    const int r0 = rowstart[n], r1 = rowstart[n + 1];
    const float dn = dinv[n];

    float2 hv = *(const float2*)&h[(size_t)n * 128 + 2 * lane];
    float2 acc;
    acc.x = hv.x * dn;
    acc.y = hv.y * dn;
    for (int i = r0; i < r1; ++i) {
        int s = adj[i];                 // wave-uniform broadcast
        float ds = dinv[s];
        float2 v = *(const float2*)&h[(size_t)s * 128 + 2 * lane];
        acc.x += v.x * ds;
        acc.y += v.y * ds;
    }
    float2 bb = *(const float2*)&bias[2 * lane];
    float vx = fmaxf(acc.x * dn + bb.x, 0.f);
    float vy = fmaxf(acc.y * dn + bb.y, 0.f);
    ushort2 ho, lo2;
    ho.x = f2bf(vx); lo2.x = f2bf(vx - bf2f(ho.x));
    ho.y = f2bf(vy); lo2.y = f2bf(vy - bf2f(ho.y));
    *(ushort2*)&hi[(size_t)n * 128 + 2 * lane] = ho;
    *(ushort2*)&lo[(size_t)n * 128 + 2 * lane] = lo2;
}

// ---------------------------------------------------------------- prep kernels
// GCN weight W [128(k)][128(n)] fp32 -> transposed n-major split-bf16 [n][k]
__global__ void k_prep_gcnw(const float* __restrict__ W,
                            unsigned short* __restrict__ hi, unsigned short* __restrict__ lo) {
    int t = blockIdx.x * 256 + threadIdx.x;
    if (t >= 16384) return;
    int k = t >> 7, n = t & 127;
    float v = W[t];
    unsigned short h = f2bf(v);
    hi[n * 128 + k] = h;
    lo[n * 128 + k] = f2bf(v - bf2f(h));
}

// LSTM prep: both w_ih and w_hh [512(r=g*128+j)][128(k)] -> packed-transposed
// split-bf16 wT[p=j*4+g][k]; bias -> bp[p] = b_ih + b_hh.
__global__ void k_prep_lstm(const float* __restrict__ w_ih, const float* __restrict__ w_hh,
                            const float* __restrict__ b_ih, const float* __restrict__ b_hh,
                            unsigned short* __restrict__ ih_hi, unsigned short* __restrict__ ih_lo,
                            unsigned short* __restrict__ hh_hi, unsigned short* __restrict__ hh_lo,
                            float* __restrict__ bp)
{
    int t = blockIdx.x * 256 + threadIdx.x;
    if (t < 65536) {
        int r = t >> 7, k = t & 127;
        int g = r >> 7, j = r & 127;
        int p = (j << 2) + g;
        float v = w_ih[t];
        unsigned short h = f2bf(v);
        ih_hi[p * 128 + k] = h;
        ih_lo[p * 128 + k] = f2bf(v - bf2f(h));
    } else if (t < 131072) {
        int t2 = t - 65536;
        int r = t2 >> 7, k = t2 & 127;
        int g = r >> 7, j = r & 127;
        int p = (j << 2) + g;
        float v = w_hh[t2];
        unsigned short h = f2bf(v);
        hh_hi[p * 128 + k] = h;
        hh_lo[p * 128 + k] = f2bf(v - bf2f(h));
    } else if (t < 131584) {
        int r = t - 131072;   // 0..511
        int g = r >> 7, j = r & 127;
        bp[(j << 2) + g] = b_ih[r] + b_hh[r];
    }
}

// ---------------------------------------------------------------- LSTM recurrence
// v5 (MFMA, SB=4): 512 thr (8 waves), 4 sequences/WG, 250 WGs (~1/CU).
// Per step: P[16x512] = h[16x128] @ W_hh^T (rows 4..15 zero-padded) via
// split-bf16 16x16x32 MFMA; wave owns 4 n-tiles.
// Phase 2: thread t -> (b=t>>7, j=t&127), one LSTM cell each; c in a register.
// Output: split-bf16 h per step (optional, feeds next gate GEMM directly) and
// compact fp32 last-step h (optional, feeds FC head).
__global__ __launch_bounds__(512, 2) void k_lstm(
    const float* __restrict__ G,            // (NB*TSEQ) x 512, gate-packed cols
    const unsigned short* __restrict__ Whi, // 512 x 128, packed-transposed hi
    const unsigned short* __restrict__ Wlo, // lo
    unsigned short* __restrict__ Hhi,       // (NB*TSEQ) x 128 bf16-hi, or nullptr
    unsigned short* __restrict__ Hlo,       // bf16-lo, or nullptr
    float* __restrict__ Hlast)              // NB x 128 fp32 (last step), or nullptr
{
    const int tid  = threadIdx.x;
    const int lane = tid & 63, wave = tid >> 6;   // 8 waves
    const int l15  = lane & 15, quad = lane >> 4;
    const int b0   = blockIdx.x * SB;

    __shared__ unsigned short Ah[16 * AHS];  // h hi (rows SB..15 stay zero)
    __shared__ unsigned short Al[16 * AHS];  // h lo
    __shared__ float part[16][516];          // P in C/D layout (row=m, col=n)

    // weight fragments: wave owns n-tiles nt0..nt0+3 (n = p = j*4+gate)
    const int nt0 = wave * 4;
    s16x8 bh[4][4], bl[4][4];   // [nt][ks]
    #pragma unroll
    for (int nt = 0; nt < 4; ++nt) {
        int p = (nt0 + nt) * 16 + l15;
        #pragma unroll
        for (int ks = 0; ks < 4; ++ks) {
            bh[nt][ks] = *(const s16x8*)&Whi[(size_t)p * 128 + ks * 32 + quad * 8];
            bl[nt][ks] = *(const s16x8*)&Wlo[(size_t)p * 128 + ks * 32 + quad * 8];
        }
    }

    for (int i = tid; i < 16 * AHS; i += 512) { Ah[i] = 0; Al[i] = 0; }

    const int j2 = tid & 127;      // phase-2 hidden unit
    const int b  = tid >> 7;       // phase-2 batch slot (0..3)
    const int bg = b0 + b;
    float c = 0.f;
    __syncthreads();

    const float* gbase = &G[((size_t)bg * TSEQ) * 512 + (j2 << 2)];

    for (int step = 0; step < TSEQ; ++step) {
        // prefetch gate input for phase 2 (independent of phase 1)
        const float4 gv = *(const float4*)&gbase[(size_t)step * 512];

        // phase 1: MFMA  P = h @ W^T  (split bf16, lo*lo dropped)
        f32x4 acc[4] = {};
        #pragma unroll
        for (int ks = 0; ks < 4; ++ks) {
            s16x8 ah = *(const s16x8*)&Ah[l15 * AHS + ks * 32 + quad * 8];
            s16x8 al = *(const s16x8*)&Al[l15 * AHS + ks * 32 + quad * 8];
            #pragma unroll
            for (int nt = 0; nt < 4; ++nt) {
                acc[nt] = __builtin_amdgcn_mfma_f32_16x16x32_bf16(ah, bh[nt][ks], acc[nt], 0, 0, 0);
                acc[nt] = __builtin_amdgcn_mfma_f32_16x16x32_bf16(al, bh[nt][ks], acc[nt], 0, 0, 0);
                acc[nt] = __builtin_amdgcn_mfma_f32_16x16x32_bf16(ah, bl[nt][ks], acc[nt], 0, 0, 0);
            }
        }
        // write P to part: row m=quad*4+r, col n=(nt0+nt)*16+l15
        #pragma unroll
        for (int nt = 0; nt < 4; ++nt)
            #pragma unroll
            for (int r = 0; r < 4; ++r)
                part[quad * 4 + r][(nt0 + nt) * 16 + l15] = acc[nt][r];
        __syncthreads();

        // phase 2: LSTM cell for the (b, j2) pair
        {
            float4 pa = *(const float4*)&part[b][j2 << 2];
            float xi = pa.x + gv.x;
            float xf = pa.y + gv.y;
            float xg = pa.z + gv.z;
            float xo = pa.w + gv.w;
            float ii = sigf(xi), ff = sigf(xf), gg = tanhfast(xg), oo = sigf(xo);
            float cn = ff * c + ii * gg;
            c = cn;
            float hn = oo * tanhfast(cn);
            unsigned short hh = f2bf(hn);
            unsigned short hl = f2bf(hn - bf2f(hh));
            Ah[b * AHS + j2] = hh;
            Al[b * AHS + j2] = hl;
            if (Hhi) {
                Hhi[((size_t)bg * TSEQ + step) * 128 + j2] = hh;
                Hlo[((size_t)bg * TSEQ + step) * 128 + j2] = hl;
            }
            if (Hlast && step == TSEQ - 1)
                Hlast[(size_t)bg * 128 + j2] = hn;
        }
        __syncthreads();
    }
}

// ---------------------------------------------------------------- FC head
// last: NB x 128 fp32 (compact last-step h)
__global__ __launch_bounds__(256) void k_fc(
    const float* __restrict__ last, const float* __restrict__ fcw,
    const float* __restrict__ fcb, float* __restrict__ out)
{
    int b    = blockIdx.x * 4 + (threadIdx.x >> 6);
    int lane = threadIdx.x & 63;
    const float* row = &last[(size_t)b * 128];
    float v = row[lane] * fcw[lane] + row[lane + 64] * fcw[lane + 64];
    #pragma unroll
    for (int off = 32; off > 0; off >>= 1)
        v += __shfl_down(v, off);
    if (lane == 0) out[b] = v + fcb[0];
}

// ---------------------------------------------------------------- launch
extern "C" void kernel_launch(void* const* d_in, const int* in_sizes, int n_in,
                              void* d_out, int out_size, void* d_ws, size_t ws_size,
                              hipStream_t stream)
{
    const float* x    = (const float*)d_in[0];
    const int*   ei   = (const int*)d_in[1];
    const float* W1   = (const float*)d_in[3];
    const float* b1   = (const float*)d_in[4];
    const float* W2   = (const float*)d_in[5];
    const float* b2   = (const float*)d_in[6];
    const float* fcw  = (const float*)d_in[7];
    const float* fcb  = (const float*)d_in[8];
    const float* wih0 = (const float*)d_in[9];
    const float* whh0 = (const float*)d_in[10];
    const float* bih0 = (const float*)d_in[11];
    const float* bhh0 = (const float*)d_in[12];
    const float* wih1 = (const float*)d_in[13];
    const float* whh1 = (const float*)d_in[14];
    const float* bih1 = (const float*)d_in[15];
    const float* bhh1 = (const float*)d_in[16];
    float* out = (float*)d_out;

    char* ws = (char*)d_ws;
    // ---- persistent regions
    unsigned short* shi = (unsigned short*)(ws + 0);          // 12.8 MB
    unsigned short* slo = (unsigned short*)(ws + 12800000);   // 12.8 MB (ends 25.6M)
    float* bufX = (float*)(ws + 25600000);                    // 0.512 MB (NB x 128; ends 26.2M)
    float* bufG = (float*)(ws + 51200000);                    // 102.4 MB (ends 153.6M)

    // ---- GCN-phase regions (inside bufG, dead before gate GEMM writes bufG)
    unsigned short* xhi = (unsigned short*)(ws + 51200000);   // 12.8 MB
    unsigned short* xlo = (unsigned short*)(ws + 64000000);   // 12.8 MB
    float* bufHg  = (float*)(ws + 76800000);                  // 25.6 MB (ends 102.4M)
    int* cnt      = (int*)(ws + 102400000);
    int* rowstart = (int*)(ws + 102604800);
    int* cursor   = (int*)(ws + 102809600);
    int* adj      = (int*)(ws + 103014400);                   // 2.4 MB (ends 105.42M)

    float* dinv = (float*)(ws + 153600000);
    float* bp0  = (float*)(ws + 153800192);
    float* bp1  = (float*)(ws + 153802240);
    unsigned short* w1t_hi   = (unsigned short*)(ws + 153804288);
    unsigned short* w1t_lo   = (unsigned short*)(ws + 153837056);
    unsigned short* w2t_hi   = (unsigned short*)(ws + 153869824);
    unsigned short* w2t_lo   = (unsigned short*)(ws + 153902592);
    unsigned short* wpih0_hi = (unsigned short*)(ws + 153935360);
    unsigned short* wpih0_lo = (unsigned short*)(ws + 154066432);
    unsigned short* wpih1_hi = (unsigned short*)(ws + 154197504);
    unsigned short* wpih1_lo = (unsigned short*)(ws + 154328576);
    unsigned short* wphh0_hi = (unsigned short*)(ws + 154459648);
    unsigned short* wphh0_lo = (unsigned short*)(ws + 154590720);
    unsigned short* wphh1_hi = (unsigned short*)(ws + 154721792);
    unsigned short* wphh1_lo = (unsigned short*)(ws + 154852864);

    // ---- CSR build + dinv
    hipMemsetAsync(cnt, 0, NND * sizeof(int), stream);
    hipMemsetAsync(cursor, 0, NND * sizeof(int), stream);
    k_count<<<(NE + 255) / 256, 256, 0, stream>>>(ei, cnt);
    k_scan<<<1, 1024, 0, stream>>>(cnt, rowstart);
    k_dinv<<<(NND + 255) / 256, 256, 0, stream>>>(cnt, dinv);
    k_fill<<<(NE + 255) / 256, 256, 0, stream>>>(ei, rowstart, cursor, adj);

    // ---- weight prep
    k_prep_gcnw<<<64, 256, 0, stream>>>(W1, w1t_hi, w1t_lo);
    k_prep_gcnw<<<64, 256, 0, stream>>>(W2, w2t_hi, w2t_lo);
    k_prep_lstm<<<514, 256, 0, stream>>>(wih0, whh0, bih0, bhh0,
                                         wpih0_hi, wpih0_lo, wphh0_hi, wphh0_lo, bp0);
    k_prep_lstm<<<514, 256, 0, stream>>>(wih1, whh1, bih1, bhh1,
                                         wpih1_hi, wpih1_lo, wphh1_hi, wphh1_lo, bp1);

    dim3 gH(391, 2);   // 128-col GEMMs (ceil(50000/128)=391)
    dim3 gG(391, 8);   // 512-col GEMMs

    // ---- GCN layer 1
    k_cvt<<<6250, 256, 0, stream>>>(x, xhi, xlo, NND * 128 / 4);
    k_gemm_mfma<<<gH, 256, 0, stream>>>(xhi, xlo, w1t_hi, w1t_lo, nullptr, bufHg, NND, 128);
    k_gather<<<NND / 4, 256, 0, stream>>>(rowstart, adj, bufHg, dinv, b1, xhi, xlo);

    // ---- GCN layer 2 (gather writes shi/slo @0-25.6M, disjoint from bufHg)
    k_gemm_mfma<<<gH, 256, 0, stream>>>(xhi, xlo, w2t_hi, w2t_lo, nullptr, bufHg, NND, 128);
    k_gather<<<NND / 4, 256, 0, stream>>>(rowstart, adj, bufHg, dinv, b2, shi, slo);

    // ---- LSTM layer 0: gate GEMM + MFMA recurrence (emits split-bf16 seq0 -> shi/slo)
    k_gemm_mfma<<<gG, 256, 0, stream>>>(shi, slo, wpih0_hi, wpih0_lo, bp0, bufG, NND, 512);
    k_lstm<<<NB / SB, 512, 0, stream>>>(bufG, wphh0_hi, wphh0_lo, shi, slo, nullptr);

    // ---- LSTM layer 1 (reads gates; emits only compact last-step fp32 -> bufX)
    k_gemm_mfma<<<gG, 256, 0, stream>>>(shi, slo, wpih1_hi, wpih1_lo, bp1, bufG, NND, 512);
    k_lstm<<<NB / SB, 512, 0, stream>>>(bufG, wphh1_hi, wphh1_lo, nullptr, nullptr, bufX);

    // ---- FC head
    k_fc<<<NB / 4, 256, 0, stream>>>(bufX, fcw, fcb, out);
}

// Round 10
// 666.776 us; speedup vs baseline: 2.2129x; 1.1252x over previous
//
#include <hip/hip_runtime.h>

// Problem constants (fixed by the reference file)
#define NND 50000   // nodes
#define NE  600000  // edges
#define TSEQ 50     // sequence length
#define NB  1000    // batch = NND/TSEQ
#define SB  4       // sequences per LSTM workgroup (250 WGs ~= 1/CU)
#define AHS 136     // LDS h-row stride in shorts (128 + 8 pad, 16B-aligned)
#define NSCB 196    // scan blocks: ceil(NND/256)

typedef __attribute__((ext_vector_type(4))) float f32x4;
typedef __attribute__((ext_vector_type(8))) short s16x8;

// ---------------------------------------------------------------- helpers
__device__ __forceinline__ float sigf(float x) {
    return 1.0f / (1.0f + __expf(-x));
}
__device__ __forceinline__ float tanhfast(float x) {
    x = fminf(fmaxf(x, -15.f), 15.f);
    float e = __expf(2.f * x);
    return (e - 1.f) / (e + 1.f);
}
// bf16 bit helpers (round-to-nearest-even)
__device__ __forceinline__ unsigned short f2bf(float f) {
    unsigned int u = __float_as_uint(f);
    u = u + 0x7FFFu + ((u >> 16) & 1u);
    return (unsigned short)(u >> 16);
}
__device__ __forceinline__ float bf2f(unsigned short h) {
    return __uint_as_float(((unsigned int)h) << 16);
}

// ---------------------------------------------------------------- CSR build
__global__ void k_count(const int* __restrict__ ei, int* __restrict__ cnt) {
    int e = blockIdx.x * 256 + threadIdx.x;
    if (e < NE) atomicAdd(&cnt[ei[NE + e]], 1);
}

__global__ void k_dinv(const int* __restrict__ cnt, float* __restrict__ dinv) {
    int i = blockIdx.x * 256 + threadIdx.x;
    if (i < NND) dinv[i] = 1.0f / sqrtf((float)cnt[i] + 1.0f);
}

// ---- 3-stage multi-block exclusive scan of cnt -> rowstart
// stage 1: per-block sums (coalesced)
__global__ __launch_bounds__(256) void k_bsum(const int* __restrict__ cnt,
                                              int* __restrict__ bsum) {
    __shared__ int red[256];
    int t = threadIdx.x;
    int idx = blockIdx.x * 256 + t;
    red[t] = (idx < NND) ? cnt[idx] : 0;
    __syncthreads();
    for (int off = 128; off > 0; off >>= 1) {
        if (t < off) red[t] += red[t + off];
        __syncthreads();
    }
    if (t == 0) bsum[blockIdx.x] = red[0];
}

// stage 2: one WG scans the NSCB block sums -> exclusive offsets
__global__ __launch_bounds__(256) void k_bscan(int* __restrict__ bsum) {
    __shared__ int ps[256];
    int t = threadIdx.x;
    int v = (t < NSCB) ? bsum[t] : 0;
    ps[t] = v;
    __syncthreads();
    for (int off = 1; off < 256; off <<= 1) {
        int u = 0;
        if (t >= off) u = ps[t - off];
        __syncthreads();
        if (t >= off) ps[t] += u;
        __syncthreads();
    }
    if (t < NSCB) bsum[t] = ps[t] - v;   // exclusive
}

// stage 3: per-block LDS scan + block offset -> rowstart (and rowstart[NND])
__global__ __launch_bounds__(256) void k_bout(const int* __restrict__ cnt,
                                              const int* __restrict__ bsum,
                                              int* __restrict__ rowstart) {
    __shared__ int ps[256];
    int t = threadIdx.x;
    int idx = blockIdx.x * 256 + t;
    int v = (idx < NND) ? cnt[idx] : 0;
    ps[t] = v;
    __syncthreads();
    for (int off = 1; off < 256; off <<= 1) {
        int u = 0;
        if (t >= off) u = ps[t - off];
        __syncthreads();
        if (t >= off) ps[t] += u;
        __syncthreads();
    }
    int boff = bsum[blockIdx.x];
    if (idx < NND) rowstart[idx] = boff + ps[t] - v;   // exclusive
    if (idx == NND - 1) rowstart[NND] = boff + ps[t];  // == NE
}

__global__ void k_fill(const int* __restrict__ ei, const int* __restrict__ rowstart,
                       int* __restrict__ cursor, int* __restrict__ adj) {
    int e = blockIdx.x * 256 + threadIdx.x;
    if (e >= NE) return;
    int s = ei[e], d = ei[NE + e];
    int pos = atomicAdd(&cursor[d], 1);
    adj[rowstart[d] + pos] = s;
}

// ---------------------------------------------------------------- cvt fp32 -> split bf16
__global__ void k_cvt(const float* __restrict__ in, unsigned short* __restrict__ hi,
                      unsigned short* __restrict__ lo, int n4) {
    int i = blockIdx.x * 256 + threadIdx.x;
    if (i >= n4) return;
    float4 v = ((const float4*)in)[i];
    ushort4 h, l;
    h.x = f2bf(v.x); l.x = f2bf(v.x - bf2f(h.x));
    h.y = f2bf(v.y); l.y = f2bf(v.y - bf2f(h.y));
    h.z = f2bf(v.z); l.z = f2bf(v.z - bf2f(h.z));
    h.w = f2bf(v.w); l.w = f2bf(v.w - bf2f(h.w));
    ((ushort4*)hi)[i] = h;
    ((ushort4*)lo)[i] = l;
}

// ---------------------------------------------------------------- MFMA GEMM
// C[M x Nc] = A[M x 128] @ B[128 x Nc] + bias, split-bf16 (3 MFMAs / tile).
// A given as hi/lo bf16 [M][128]; B given TRANSPOSED n-major hi/lo [Nc][128].
// 256 thr, tile 128x64, 4 waves: wave = (mw = w&1 -> 64 rows, nw = w>>1 -> 32 cols).
__global__ __launch_bounds__(256) void k_gemm_mfma(
    const unsigned short* __restrict__ Ahi, const unsigned short* __restrict__ Alo,
    const unsigned short* __restrict__ Bhi, const unsigned short* __restrict__ Blo,
    const float* __restrict__ bias, float* __restrict__ C,
    int M, int Nc)
{
    __shared__ unsigned short As_hi[128][72];
    __shared__ unsigned short As_lo[128][72];
    __shared__ unsigned short Bs_hi[64][72];
    __shared__ unsigned short Bs_lo[64][72];

    const int tid  = threadIdx.x;
    const int lane = tid & 63, wave = tid >> 6;
    const int mw = wave & 1, nw = wave >> 1;
    const int l15 = lane & 15, quad = lane >> 4;
    const int rowBase = blockIdx.x * 128;
    const int colBase = blockIdx.y * 64;

    f32x4 acc[4][2] = {};

    for (int kc = 0; kc < 128; kc += 64) {
        // stage A (128 rows x 64 k) and B (64 n-rows x 64 k), 16B copies
        int lr = tid >> 3;            // 0..31
        int ko = (tid & 7) * 8;       // 0..56
        #pragma unroll
        for (int i = 0; i < 4; ++i) {
            int row = lr + i * 32;
            int g = rowBase + row;
            uint4 vh = make_uint4(0, 0, 0, 0), vl = make_uint4(0, 0, 0, 0);
            if (g < M) {
                vh = *(const uint4*)&Ahi[(size_t)g * 128 + kc + ko];
                vl = *(const uint4*)&Alo[(size_t)g * 128 + kc + ko];
            }
            *(uint4*)&As_hi[row][ko] = vh;
            *(uint4*)&As_lo[row][ko] = vl;
        }
        #pragma unroll
        for (int i = 0; i < 2; ++i) {
            int row = lr + i * 32;        // n within tile (Nc is a multiple of 64)
            int g = colBase + row;
            uint4 vh = *(const uint4*)&Bhi[(size_t)g * 128 + kc + ko];
            uint4 vl = *(const uint4*)&Blo[(size_t)g * 128 + kc + ko];
            *(uint4*)&Bs_hi[row][ko] = vh;
            *(uint4*)&Bs_lo[row][ko] = vl;
        }
        __syncthreads();

        #pragma unroll
        for (int kq = 0; kq < 2; ++kq) {
            int kof = kq * 32 + quad * 8;
            s16x8 ah[4], al[4], bh[2], bl[2];
            #pragma unroll
            for (int ms = 0; ms < 4; ++ms) {
                int r = mw * 64 + ms * 16 + l15;
                ah[ms] = *(const s16x8*)&As_hi[r][kof];
                al[ms] = *(const s16x8*)&As_lo[r][kof];
            }
            #pragma unroll
            for (int ns = 0; ns < 2; ++ns) {
                int r = nw * 32 + ns * 16 + l15;
                bh[ns] = *(const s16x8*)&Bs_hi[r][kof];
                bl[ns] = *(const s16x8*)&Bs_lo[r][kof];
            }
            #pragma unroll
            for (int ms = 0; ms < 4; ++ms)
                #pragma unroll
                for (int ns = 0; ns < 2; ++ns)
                    acc[ms][ns] = __builtin_amdgcn_mfma_f32_16x16x32_bf16(ah[ms], bh[ns], acc[ms][ns], 0, 0, 0);
            #pragma unroll
            for (int ms = 0; ms < 4; ++ms)
                #pragma unroll
                for (int ns = 0; ns < 2; ++ns)
                    acc[ms][ns] = __builtin_amdgcn_mfma_f32_16x16x32_bf16(al[ms], bh[ns], acc[ms][ns], 0, 0, 0);
            #pragma unroll
            for (int ms = 0; ms < 4; ++ms)
                #pragma unroll
                for (int ns = 0; ns < 2; ++ns)
                    acc[ms][ns] = __builtin_amdgcn_mfma_f32_16x16x32_bf16(ah[ms], bl[ns], acc[ms][ns], 0, 0, 0);
        }
        __syncthreads();
    }

    // epilogue: C/D layout col=lane&15, row=quad*4+reg
    #pragma unroll
    for (int ns = 0; ns < 2; ++ns) {
        int col = colBase + nw * 32 + ns * 16 + l15;
        float bv = bias ? bias[col] : 0.f;
        #pragma unroll
        for (int ms = 0; ms < 4; ++ms) {
            int row0 = rowBase + mw * 64 + ms * 16 + quad * 4;
            #pragma unroll
            for (int r = 0; r < 4; ++r) {
                int row = row0 + r;
                if (row < M) C[(size_t)row * Nc + col] = acc[ms][ns][r] + bv;
            }
        }
    }
}

// ---------------------------------------------------------------- GCN gather
// One wave per node; lane owns 2 cols (float2). agg = dn*(sum_s h[s]*ds + h[n]*dn),
// fused bias + relu + split-bf16 output (feeds the next MFMA GEMM directly).
// NOTE: hi/lo output MUST NOT alias h (blocks read arbitrary h rows).
__global__ __launch_bounds__(256) void k_gather(
    const int* __restrict__ rowstart, const int* __restrict__ adj,
    const float* __restrict__ h, const float* __restrict__ dinv,
    const float* __restrict__ bias,
    unsigned short* __restrict__ hi, unsigned short* __restrict__ lo)
{
    const int n    = blockIdx.x * 4 + (threadIdx.x >> 6);   // grid exactly NND/4
    const int lane = threadIdx.x & 63;
    const int r0 = rowstart[n], r1 = rowstart[n + 1];
    const float dn = dinv[n];

    float2 hv = *(const float2*)&h[(size_t)n * 128 + 2 * lane];
    float2 acc;
    acc.x = hv.x * dn;
    acc.y = hv.y * dn;
    for (int i = r0; i < r1; ++i) {
        int s = adj[i];                 // wave-uniform broadcast
        float ds = dinv[s];
        float2 v = *(const float2*)&h[(size_t)s * 128 + 2 * lane];
        acc.x += v.x * ds;
        acc.y += v.y * ds;
    }
    float2 bb = *(const float2*)&bias[2 * lane];
    float vx = fmaxf(acc.x * dn + bb.x, 0.f);
    float vy = fmaxf(acc.y * dn + bb.y, 0.f);
    ushort2 ho, lo2;
    ho.x = f2bf(vx); lo2.x = f2bf(vx - bf2f(ho.x));
    ho.y = f2bf(vy); lo2.y = f2bf(vy - bf2f(ho.y));
    *(ushort2*)&hi[(size_t)n * 128 + 2 * lane] = ho;
    *(ushort2*)&lo[(size_t)n * 128 + 2 * lane] = lo2;
}

// ---------------------------------------------------------------- prep kernels
// GCN weight W [128(k)][128(n)] fp32 -> transposed n-major split-bf16 [n][k]
__global__ void k_prep_gcnw(const float* __restrict__ W,
                            unsigned short* __restrict__ hi, unsigned short* __restrict__ lo) {
    int t = blockIdx.x * 256 + threadIdx.x;
    if (t >= 16384) return;
    int k = t >> 7, n = t & 127;
    float v = W[t];
    unsigned short h = f2bf(v);
    hi[n * 128 + k] = h;
    lo[n * 128 + k] = f2bf(v - bf2f(h));
}

// LSTM prep: both w_ih and w_hh [512(r=g*128+j)][128(k)] -> packed-transposed
// split-bf16 wT[p=j*4+g][k]; bias -> bp[p] = b_ih + b_hh.
__global__ void k_prep_lstm(const float* __restrict__ w_ih, const float* __restrict__ w_hh,
                            const float* __restrict__ b_ih, const float* __restrict__ b_hh,
                            unsigned short* __restrict__ ih_hi, unsigned short* __restrict__ ih_lo,
                            unsigned short* __restrict__ hh_hi, unsigned short* __restrict__ hh_lo,
                            float* __restrict__ bp)
{
    int t = blockIdx.x * 256 + threadIdx.x;
    if (t < 65536) {
        int r = t >> 7, k = t & 127;
        int g = r >> 7, j = r & 127;
        int p = (j << 2) + g;
        float v = w_ih[t];
        unsigned short h = f2bf(v);
        ih_hi[p * 128 + k] = h;
        ih_lo[p * 128 + k] = f2bf(v - bf2f(h));
    } else if (t < 131072) {
        int t2 = t - 65536;
        int r = t2 >> 7, k = t2 & 127;
        int g = r >> 7, j = r & 127;
        int p = (j << 2) + g;
        float v = w_hh[t2];
        unsigned short h = f2bf(v);
        hh_hi[p * 128 + k] = h;
        hh_lo[p * 128 + k] = f2bf(v - bf2f(h));
    } else if (t < 131584) {
        int r = t - 131072;   // 0..511
        int g = r >> 7, j = r & 127;
        bp[(j << 2) + g] = b_ih[r] + b_hh[r];
    }
}

// ---------------------------------------------------------------- LSTM recurrence
// v5 (MFMA, SB=4): 512 thr (8 waves), 4 sequences/WG, 250 WGs (~1/CU).
// Per step: P[16x512] = h[16x128] @ W_hh^T (rows 4..15 zero-padded) via
// split-bf16 16x16x32 MFMA; wave owns 4 n-tiles.
// Phase 2: thread t -> (b=t>>7, j=t&127), one LSTM cell each; c in a register.
// Output: split-bf16 h per step (optional, feeds next gate GEMM directly) and
// compact fp32 last-step h (optional, feeds FC head).
__global__ __launch_bounds__(512, 2) void k_lstm(
    const float* __restrict__ G,            // (NB*TSEQ) x 512, gate-packed cols
    const unsigned short* __restrict__ Whi, // 512 x 128, packed-transposed hi
    const unsigned short* __restrict__ Wlo, // lo
    unsigned short* __restrict__ Hhi,       // (NB*TSEQ) x 128 bf16-hi, or nullptr
    unsigned short* __restrict__ Hlo,       // bf16-lo, or nullptr
    float* __restrict__ Hlast)              // NB x 128 fp32 (last step), or nullptr
{
    const int tid  = threadIdx.x;
    const int lane = tid & 63, wave = tid >> 6;   // 8 waves
    const int l15  = lane & 15, quad = lane >> 4;
    const int b0   = blockIdx.x * SB;

    __shared__ unsigned short Ah[16 * AHS];  // h hi (rows SB..15 stay zero)
    __shared__ unsigned short Al[16 * AHS];  // h lo
    __shared__ float part[16][516];          // P in C/D layout (row=m, col=n)

    // weight fragments: wave owns n-tiles nt0..nt0+3 (n = p = j*4+gate)
    const int nt0 = wave * 4;
    s16x8 bh[4][4], bl[4][4];   // [nt][ks]
    #pragma unroll
    for (int nt = 0; nt < 4; ++nt) {
        int p = (nt0 + nt) * 16 + l15;
        #pragma unroll
        for (int ks = 0; ks < 4; ++ks) {
            bh[nt][ks] = *(const s16x8*)&Whi[(size_t)p * 128 + ks * 32 + quad * 8];
            bl[nt][ks] = *(const s16x8*)&Wlo[(size_t)p * 128 + ks * 32 + quad * 8];
        }
    }

    for (int i = tid; i < 16 * AHS; i += 512) { Ah[i] = 0; Al[i] = 0; }

    const int j2 = tid & 127;      // phase-2 hidden unit
    const int b  = tid >> 7;       // phase-2 batch slot (0..3)
    const int bg = b0 + b;
    float c = 0.f;
    __syncthreads();

    const float* gbase = &G[((size_t)bg * TSEQ) * 512 + (j2 << 2)];

    for (int step = 0; step < TSEQ; ++step) {
        // prefetch gate input for phase 2 (independent of phase 1)
        const float4 gv = *(const float4*)&gbase[(size_t)step * 512];

        // phase 1: MFMA  P = h @ W^T  (split bf16, lo*lo dropped)
        f32x4 acc[4] = {};
        #pragma unroll
        for (int ks = 0; ks < 4; ++ks) {
            s16x8 ah = *(const s16x8*)&Ah[l15 * AHS + ks * 32 + quad * 8];
            s16x8 al = *(const s16x8*)&Al[l15 * AHS + ks * 32 + quad * 8];
            #pragma unroll
            for (int nt = 0; nt < 4; ++nt) {
                acc[nt] = __builtin_amdgcn_mfma_f32_16x16x32_bf16(ah, bh[nt][ks], acc[nt], 0, 0, 0);
                acc[nt] = __builtin_amdgcn_mfma_f32_16x16x32_bf16(al, bh[nt][ks], acc[nt], 0, 0, 0);
                acc[nt] = __builtin_amdgcn_mfma_f32_16x16x32_bf16(ah, bl[nt][ks], acc[nt], 0, 0, 0);
            }
        }
        // write P to part: row m=quad*4+r, col n=(nt0+nt)*16+l15
        #pragma unroll
        for (int nt = 0; nt < 4; ++nt)
            #pragma unroll
            for (int r = 0; r < 4; ++r)
                part[quad * 4 + r][(nt0 + nt) * 16 + l15] = acc[nt][r];
        __syncthreads();

        // phase 2: LSTM cell for the (b, j2) pair
        {
            float4 pa = *(const float4*)&part[b][j2 << 2];
            float xi = pa.x + gv.x;
            float xf = pa.y + gv.y;
            float xg = pa.z + gv.z;
            float xo = pa.w + gv.w;
            float ii = sigf(xi), ff = sigf(xf), gg = tanhfast(xg), oo = sigf(xo);
            float cn = ff * c + ii * gg;
            c = cn;
            float hn = oo * tanhfast(cn);
            unsigned short hh = f2bf(hn);
            unsigned short hl = f2bf(hn - bf2f(hh));
            Ah[b * AHS + j2] = hh;
            Al[b * AHS + j2] = hl;
            if (Hhi) {
                Hhi[((size_t)bg * TSEQ + step) * 128 + j2] = hh;
                Hlo[((size_t)bg * TSEQ + step) * 128 + j2] = hl;
            }
            if (Hlast && step == TSEQ - 1)
                Hlast[(size_t)bg * 128 + j2] = hn;
        }
        __syncthreads();
    }
}

// ---------------------------------------------------------------- FC head
// last: NB x 128 fp32 (compact last-step h)
__global__ __launch_bounds__(256) void k_fc(
    const float* __restrict__ last, const float* __restrict__ fcw,
    const float* __restrict__ fcb, float* __restrict__ out)
{
    int b    = blockIdx.x * 4 + (threadIdx.x >> 6);
    int lane = threadIdx.x & 63;
    const float* row = &last[(size_t)b * 128];
    float v = row[lane] * fcw[lane] + row[lane + 64] * fcw[lane + 64];
    #pragma unroll
    for (int off = 32; off > 0; off >>= 1)
        v += __shfl_down(v, off);
    if (lane == 0) out[b] = v + fcb[0];
}

// ---------------------------------------------------------------- launch
extern "C" void kernel_launch(void* const* d_in, const int* in_sizes, int n_in,
                              void* d_out, int out_size, void* d_ws, size_t ws_size,
                              hipStream_t stream)
{
    const float* x    = (const float*)d_in[0];
    const int*   ei   = (const int*)d_in[1];
    const float* W1   = (const float*)d_in[3];
    const float* b1   = (const float*)d_in[4];
    const float* W2   = (const float*)d_in[5];
    const float* b2   = (const float*)d_in[6];
    const float* fcw  = (const float*)d_in[7];
    const float* fcb  = (const float*)d_in[8];
    const float* wih0 = (const float*)d_in[9];
    const float* whh0 = (const float*)d_in[10];
    const float* bih0 = (const float*)d_in[11];
    const float* bhh0 = (const float*)d_in[12];
    const float* wih1 = (const float*)d_in[13];
    const float* whh1 = (const float*)d_in[14];
    const float* bih1 = (const float*)d_in[15];
    const float* bhh1 = (const float*)d_in[16];
    float* out = (float*)d_out;

    char* ws = (char*)d_ws;
    // ---- persistent regions
    unsigned short* shi = (unsigned short*)(ws + 0);          // 12.8 MB
    unsigned short* slo = (unsigned short*)(ws + 12800000);   // 12.8 MB (ends 25.6M)
    float* bufX = (float*)(ws + 25600000);                    // 0.512 MB (NB x 128; ends 26.2M)
    float* bufG = (float*)(ws + 51200000);                    // 102.4 MB (ends 153.6M)

    // ---- GCN-phase regions (inside bufG, dead before gate GEMM writes bufG)
    unsigned short* xhi = (unsigned short*)(ws + 51200000);   // 12.8 MB
    unsigned short* xlo = (unsigned short*)(ws + 64000000);   // 12.8 MB
    float* bufHg  = (float*)(ws + 76800000);                  // 25.6 MB (ends 102.4M)
    int* cnt      = (int*)(ws + 102400000);
    int* rowstart = (int*)(ws + 102604800);
    int* cursor   = (int*)(ws + 102809600);
    int* adj      = (int*)(ws + 103014400);                   // 2.4 MB (ends 105.42M)
    int* bsum     = (int*)(ws + 105420800);                   // NSCB ints

    float* dinv = (float*)(ws + 153600000);
    float* bp0  = (float*)(ws + 153800192);
    float* bp1  = (float*)(ws + 153802240);
    unsigned short* w1t_hi   = (unsigned short*)(ws + 153804288);
    unsigned short* w1t_lo   = (unsigned short*)(ws + 153837056);
    unsigned short* w2t_hi   = (unsigned short*)(ws + 153869824);
    unsigned short* w2t_lo   = (unsigned short*)(ws + 153902592);
    unsigned short* wpih0_hi = (unsigned short*)(ws + 153935360);
    unsigned short* wpih0_lo = (unsigned short*)(ws + 154066432);
    unsigned short* wpih1_hi = (unsigned short*)(ws + 154197504);
    unsigned short* wpih1_lo = (unsigned short*)(ws + 154328576);
    unsigned short* wphh0_hi = (unsigned short*)(ws + 154459648);
    unsigned short* wphh0_lo = (unsigned short*)(ws + 154590720);
    unsigned short* wphh1_hi = (unsigned short*)(ws + 154721792);
    unsigned short* wphh1_lo = (unsigned short*)(ws + 154852864);

    // ---- CSR build + dinv (multi-block scan)
    hipMemsetAsync(cnt, 0, NND * sizeof(int), stream);
    hipMemsetAsync(cursor, 0, NND * sizeof(int), stream);
    k_count<<<(NE + 255) / 256, 256, 0, stream>>>(ei, cnt);
    k_bsum<<<NSCB, 256, 0, stream>>>(cnt, bsum);
    k_bscan<<<1, 256, 0, stream>>>(bsum);
    k_bout<<<NSCB, 256, 0, stream>>>(cnt, bsum, rowstart);
    k_dinv<<<(NND + 255) / 256, 256, 0, stream>>>(cnt, dinv);
    k_fill<<<(NE + 255) / 256, 256, 0, stream>>>(ei, rowstart, cursor, adj);

    // ---- weight prep
    k_prep_gcnw<<<64, 256, 0, stream>>>(W1, w1t_hi, w1t_lo);
    k_prep_gcnw<<<64, 256, 0, stream>>>(W2, w2t_hi, w2t_lo);
    k_prep_lstm<<<514, 256, 0, stream>>>(wih0, whh0, bih0, bhh0,
                                         wpih0_hi, wpih0_lo, wphh0_hi, wphh0_lo, bp0);
    k_prep_lstm<<<514, 256, 0, stream>>>(wih1, whh1, bih1, bhh1,
                                         wpih1_hi, wpih1_lo, wphh1_hi, wphh1_lo, bp1);

    dim3 gH(391, 2);   // 128-col GEMMs (ceil(50000/128)=391)
    dim3 gG(391, 8);   // 512-col GEMMs

    // ---- GCN layer 1
    k_cvt<<<6250, 256, 0, stream>>>(x, xhi, xlo, NND * 128 / 4);
    k_gemm_mfma<<<gH, 256, 0, stream>>>(xhi, xlo, w1t_hi, w1t_lo, nullptr, bufHg, NND, 128);
    k_gather<<<NND / 4, 256, 0, stream>>>(rowstart, adj, bufHg, dinv, b1, xhi, xlo);

    // ---- GCN layer 2 (gather writes shi/slo @0-25.6M, disjoint from bufHg)
    k_gemm_mfma<<<gH, 256, 0, stream>>>(xhi, xlo, w2t_hi, w2t_lo, nullptr, bufHg, NND, 128);
    k_gather<<<NND / 4, 256, 0, stream>>>(rowstart, adj, bufHg, dinv, b2, shi, slo);

    // ---- LSTM layer 0: gate GEMM + MFMA recurrence (emits split-bf16 seq0 -> shi/slo)
    k_gemm_mfma<<<gG, 256, 0, stream>>>(shi, slo, wpih0_hi, wpih0_lo, bp0, bufG, NND, 512);
    k_lstm<<<NB / SB, 512, 0, stream>>>(bufG, wphh0_hi, wphh0_lo, shi, slo, nullptr);

    // ---- LSTM layer 1 (reads gates; emits only compact last-step fp32 -> bufX)
    k_gemm_mfma<<<gG, 256, 0, stream>>>(shi, slo, wpih1_hi, wpih1_lo, bp1, bufG, NND, 512);
    k_lstm<<<NB / SB, 512, 0, stream>>>(bufG, wphh1_hi, wphh1_lo, nullptr, nullptr, bufX);

    // ---- FC head
    k_fc<<<NB / 4, 256, 0, stream>>>(bufX, fcw, fcb, out);
}